// Round 1
// baseline (1057.761 us; speedup 1.0000x reference)
//
#include <hip/hip_runtime.h>
#include <hip/hip_bf16.h>
#include <math.h>

#define B_   16
#define D_   192
#define TX_  512
#define TY_  2048
#define NEGV (-1e9f)

// -------- workspace layout (bytes) --------
// S    : B*D*TX f32   @ 0          (6,291,456)
// MS   : B*D*TX f32   @ 6291456    (6,291,456)
// NC   : B*TY*TX f32  @ 12615680   (67,108,864)
// dirs : B*2048*64 u8 @ 79724544   (2,097,152)   [aliased: Cpart B*6*TX f32 in
//         first 196,608 B — consumed by gemm_nc BEFORE mas_forward writes dirs]
// path : B*TY  i32    @ 81821696   (131,072)

// -------- output layout (f32 elements) --------
// out_main [B,384,TY] @ 0, l_length [B] @ 12582912, attn [B,TY,TX] @ 12582928

typedef __attribute__((address_space(1))) const float glob_f;
typedef __attribute__((address_space(3))) float       lds_f;

// ============ Kernel A: precompute S, MS, partial C (deterministic) ============
__global__ __launch_bounds__(512) void precomp(const float* __restrict__ xm,
                                               const float* __restrict__ xl,
                                               float* __restrict__ S,
                                               float* __restrict__ MS,
                                               float* __restrict__ Cpart) {
    int b = blockIdx.x;
    int p = blockIdx.y;
    int x = threadIdx.x;
    size_t base = ((size_t)b * D_ + p * 32) * TX_;
    const float* mb = xm + base;
    const float* lb = xl + base;
    float* Sb  = S  + base;
    float* MSb = MS + base;
    float c = 0.f;
    for (int d = 0; d < 32; d++) {
        float lg = lb[d * TX_ + x];
        float mn = mb[d * TX_ + x];
        float s  = expf(-2.f * lg);
        float ms = mn * s;
        Sb[d * TX_ + x]  = s;
        MSb[d * TX_ + x] = ms;
        c += -0.9189385332046727f - lg - 0.5f * mn * mn * s;   // nc1 + nc4 terms
    }
    Cpart[(b * 6 + p) * TX_ + x] = c;
}

// ============ Kernel B: NC = A(z)*B(s,ms) + c, f32 128x128 tile, 8x8 micro ============
// unroll 2 on kk: keeps live set ~160 VGPR (R3's full unroll spilled at 256).
__global__ __launch_bounds__(256) void gemm_nc(const float* __restrict__ z,
                                               const float* __restrict__ S,
                                               const float* __restrict__ MS,
                                               const float* __restrict__ Cpart,
                                               float* __restrict__ NC) {
    int bx = blockIdx.x;            // 4  -> x tiles of 128
    int by = blockIdx.y;            // 16 -> y tiles of 128
    int b  = blockIdx.z;            // 16
    int tid = threadIdx.x;
    int tx = tid & 15, ty = tid >> 4;
    __shared__ __align__(16) float Zt[16 * 128];
    __shared__ __align__(16) float St[16 * 128];
    __shared__ __align__(16) float MSt[16 * 128];

    float acc[8][8];
#pragma unroll
    for (int i = 0; i < 8; i++)
#pragma unroll
        for (int j = 0; j < 8; j++) acc[i][j] = 0.f;

    int x0 = bx * 128, y0 = by * 128;
    const float* zb  = z  + (size_t)b * D_ * TY_;
    const float* Sb  = S  + (size_t)b * D_ * TX_;
    const float* MSb = MS + (size_t)b * D_ * TX_;

    for (int k0 = 0; k0 < D_; k0 += 16) {
        // stage 3 x (16 rows x 128 cols) via async global->LDS, 16B per lane
#pragma unroll
        for (int j = 0; j < 2; j++) {
            int f = tid + j * 256;          // 0..511 float4 slots
            int kk = f >> 5, c = (f & 31) * 4;
            __builtin_amdgcn_global_load_lds((glob_f*)(zb  + (size_t)(k0 + kk) * TY_ + y0 + c),
                                             (lds_f*)(Zt  + f * 4), 16, 0, 0);
            __builtin_amdgcn_global_load_lds((glob_f*)(Sb  + (size_t)(k0 + kk) * TX_ + x0 + c),
                                             (lds_f*)(St  + f * 4), 16, 0, 0);
            __builtin_amdgcn_global_load_lds((glob_f*)(MSb + (size_t)(k0 + kk) * TX_ + x0 + c),
                                             (lds_f*)(MSt + f * 4), 16, 0, 0);
        }
        __syncthreads();

#pragma unroll 2
        for (int kk = 0; kk < 16; kk++) {
            float4 z0 = *(const float4*)&Zt[kk * 128 + ty * 4];
            float4 z1 = *(const float4*)&Zt[kk * 128 + 64 + ty * 4];
            float4 s0 = *(const float4*)&St[kk * 128 + tx * 4];
            float4 s1 = *(const float4*)&St[kk * 128 + 64 + tx * 4];
            float4 m0 = *(const float4*)&MSt[kk * 128 + tx * 4];
            float4 m1 = *(const float4*)&MSt[kk * 128 + 64 + tx * 4];
            float4 u0, u1;
            u0.x = -0.5f * z0.x * z0.x; u0.y = -0.5f * z0.y * z0.y;
            u0.z = -0.5f * z0.z * z0.z; u0.w = -0.5f * z0.w * z0.w;
            u1.x = -0.5f * z1.x * z1.x; u1.y = -0.5f * z1.y * z1.y;
            u1.z = -0.5f * z1.z * z1.z; u1.w = -0.5f * z1.w * z1.w;
            float zz[8] = {z0.x, z0.y, z0.z, z0.w, z1.x, z1.y, z1.z, z1.w};
            float uu[8] = {u0.x, u0.y, u0.z, u0.w, u1.x, u1.y, u1.z, u1.w};
            float ss[8] = {s0.x, s0.y, s0.z, s0.w, s1.x, s1.y, s1.z, s1.w};
            float mm[8] = {m0.x, m0.y, m0.z, m0.w, m1.x, m1.y, m1.z, m1.w};
#pragma unroll
            for (int i = 0; i < 8; i++)
#pragma unroll
                for (int j = 0; j < 8; j++)
                    acc[i][j] += uu[i] * ss[j] + zz[i] * mm[j];
        }
        __syncthreads();
    }

    // column constants: sum 6 deterministic partials
    float cv[8] = {0, 0, 0, 0, 0, 0, 0, 0};
#pragma unroll
    for (int p = 0; p < 6; p++) {
        float4 c0 = *(const float4*)&Cpart[(b * 6 + p) * TX_ + x0 + tx * 4];
        float4 c1 = *(const float4*)&Cpart[(b * 6 + p) * TX_ + x0 + 64 + tx * 4];
        cv[0] += c0.x; cv[1] += c0.y; cv[2] += c0.z; cv[3] += c0.w;
        cv[4] += c1.x; cv[5] += c1.y; cv[6] += c1.z; cv[7] += c1.w;
    }

#pragma unroll
    for (int i = 0; i < 8; i++) {
        int y = y0 + ty * 4 + (i & 3) + 64 * (i >> 2);
        float4 o0, o1;
        o0.x = acc[i][0] + cv[0]; o0.y = acc[i][1] + cv[1];
        o0.z = acc[i][2] + cv[2]; o0.w = acc[i][3] + cv[3];
        o1.x = acc[i][4] + cv[4]; o1.y = acc[i][5] + cv[5];
        o1.z = acc[i][6] + cv[6]; o1.w = acc[i][7] + cv[7];
        *(float4*)&NC[((size_t)b * TY_ + y) * TX_ + x0 + tx * 4]      = o0;
        *(float4*)&NC[((size_t)b * TY_ + y) * TX_ + x0 + 64 + tx * 4] = o1;
    }
}

// ============ Kernel C: MAS forward DP — LDS ring prefetch, counted vmcnt ============
// R5 redesign: the R4 register ring (16x2 float4 = 128 VGPR) was silently
// de-pipelined by the compiler (rocprof: VGPR=136 < 150 needed -> loads sunk
// to uses -> 308 cy/row = L2 latency per row). In-flight data now lives in a
// 16-row x 2KB LDS ring via global_load_lds (zero VGPR cost, compiler cannot
// re-sink it). Discipline:
//  - prefetch distance PF=12 rows; 3 VMEM ops/row (2 gload_lds + 1 byte store)
//    in one in-order vmcnt stream -> gload(y+2) has exactly 1+3*(PF-3)=28
//    newer ops -> s_waitcnt vmcnt(28) before the ds_read of row y+2.
//  - ds_read row y+2 while computing row y (3-buffer rotation, unroll x3):
//    ~2 rows (~200+ cy) cover the ~120 cy single-outstanding LDS latency.
//  - prologue stages rows 1..PF and drains vmcnt(0) once; first forced wait
//    is exactly at row 11 (28 newer ops) -> counting stays exact.
// Early-shfl kept: v[7] computed first, shfl_up issued immediately, consumed
// next row.
#define RING 16
#define PF   12

__global__ __launch_bounds__(64, 1) void mas_forward(const float* __restrict__ NC,
                                                     unsigned char* __restrict__ dirs) {
    int b = blockIdx.x;
    int lane = threadIdx.x;
    const float* ncb = NC + (size_t)b * TY_ * TX_;
    __shared__ __align__(16) float ring[RING * TX_];

    float v[8];
#pragma unroll
    for (int j = 0; j < 8; j++) v[j] = NEGV;
    if (lane == 0) v[0] = ncb[0];

    unsigned char* db = dirs + (size_t)b * 2048 * 64 + lane;
    float bound = NEGV;   // pending shfl result: lane-1's v[7] after previous row

    auto stage = [&](int row) {
        int slot = row & (RING - 1);
        const float* src = ncb + (size_t)row * TX_ + lane * 4;   // 16 B per lane
        __builtin_amdgcn_global_load_lds((glob_f*)src,
                                         (lds_f*)&ring[slot * TX_], 16, 0, 0);
        __builtin_amdgcn_global_load_lds((glob_f*)(src + 256),
                                         (lds_f*)&ring[slot * TX_ + 256], 16, 0, 0);
    };

    auto lds_row = [&](int row, float4& a, float4& c) {
        int slot = row & (RING - 1);
        a = *(const float4*)&ring[slot * TX_ + lane * 8];
        c = *(const float4*)&ring[slot * TX_ + lane * 8 + 4];
    };

    auto row_step = [&](float4 a, float4 c, int y, bool mask) {
        float ncv[8] = {a.x, a.y, a.z, a.w, c.x, c.y, c.z, c.w};
        float vd0 = (lane == 0) ? NEGV : bound;
        // element 7 first: compute, mask, and launch the cross-lane transfer
        float v6o = v[6], v7o = v[7];
        float v7n = ncv[7] + fmaxf(v7o, v6o);
        if (mask && y < 511 && lane * 8 + 7 > y) v7n = NEGV;
        bound = __shfl_up(v7n, 1);               // consumed at next row's vd0
        unsigned bits = (v6o > v7o) ? 0x80u : 0u;
        float vd = vd0;
#pragma unroll
        for (int j = 0; j < 7; j++) {
            float vp = v[j];
            bits |= (vd > vp) ? (1u << j) : 0u;
            v[j] = ncv[j] + fmaxf(vp, vd);
            vd = vp;
        }
        if (mask && y < 511) {
            int xb = lane * 8;
#pragma unroll
            for (int j = 0; j < 7; j++)
                if (xb + j > y) v[j] = NEGV;
        }
        v[7] = v7n;
        db[(size_t)(y - 1) * 64] = (unsigned char)bits;
    };

    // prologue: stage rows 1..PF, drain once, preload rows 1,2 into regs
#pragma unroll
    for (int r = 1; r <= PF; r++) stage(r);
    asm volatile("s_waitcnt vmcnt(0)" ::: "memory");

    float4 a0, c0, a1, c1, a2, c2;
    lds_row(1, a0, c0);
    lds_row(2, a1, c1);

    int y = 1;
    // masked phase: 170 triples -> rows 1..510 (all have y < 511)
    for (int t = 0; t < 170; t++) {
        asm volatile("s_waitcnt vmcnt(28)" ::: "memory");
        lds_row(y + 2, a2, c2);
        stage(y + PF);
        row_step(a0, c0, y, true); y++;

        asm volatile("s_waitcnt vmcnt(28)" ::: "memory");
        lds_row(y + 2, a0, c0);
        stage(y + PF);
        row_step(a1, c1, y, true); y++;

        asm volatile("s_waitcnt vmcnt(28)" ::: "memory");
        lds_row(y + 2, a1, c1);
        stage(y + PF);
        row_step(a2, c2, y, true); y++;
    }
    // unmasked phase: 512 triples -> rows 511..2046 (zero masking VALU)
    for (int t = 0; t < 512; t++) {
        asm volatile("s_waitcnt vmcnt(28)" ::: "memory");
        lds_row(y + 2, a2, c2);
        stage(min(y + PF, TY_ - 1));
        row_step(a0, c0, y, false); y++;

        asm volatile("s_waitcnt vmcnt(28)" ::: "memory");
        lds_row(min(y + 2, TY_ - 1), a0, c0);
        stage(min(y + PF, TY_ - 1));
        row_step(a1, c1, y, false); y++;

        asm volatile("s_waitcnt vmcnt(28)" ::: "memory");
        lds_row(min(y + 2, TY_ - 1), a1, c1);
        stage(min(y + PF, TY_ - 1));
        row_step(a2, c2, y, false); y++;
    }
    // y == 2047: a0 holds row 2047 (read in the last triple's sub2)
    row_step(a0, c0, 2047, false);
}

// ============ Kernel D: backtrack (one wave per sample, shfl-windowed) ============
__global__ __launch_bounds__(64, 1) void mas_backtrack(const unsigned* __restrict__ dirs,
                                                       int* __restrict__ path) {
    int b = blockIdx.x;
    int lane = threadIdx.x;
    const unsigned* db = dirs + (size_t)b * 2048 * 16;   // 16 dwords per row
    int idx = TX_ - 1;                                   // path[2047]

    for (int y_hi = 2047; y_hi >= 1; y_hi -= 64) {
        int wb = (idx >> 5) - 2;
        if (wb < 0) wb = 0;
        int base = wb << 5;
        int y = y_hi - lane;
        unsigned w0 = 0, w1 = 0, w2 = 0;
        if (y >= 1) {
            const unsigned* r = db + (size_t)(y - 1) * 16 + wb;
            w0 = r[0]; w1 = r[1]; w2 = r[2];
        }
        int steps = (y_hi < 64) ? y_hi : 64;
        int my_path = 0;
#pragma unroll 8
        for (int t = 0; t < steps; t++) {
            if (lane == t) my_path = idx;
            unsigned u0 = (unsigned)__shfl((int)w0, t);
            unsigned u1 = (unsigned)__shfl((int)w1, t);
            unsigned u2 = (unsigned)__shfl((int)w2, t);
            int off = idx - base;
            unsigned w = (off < 32) ? u0 : ((off < 64) ? u1 : u2);
            idx -= (int)((w >> (off & 31)) & 1u);
        }
        if (lane < steps) path[b * TY_ + (y_hi - lane)] = my_path;
    }
    if (lane == 0) path[b * TY_ + 0] = idx;
}

// ============ Kernel E: durations + l_length ============
__global__ __launch_bounds__(512) void durations_ll(const int* __restrict__ path,
                                                    const float* __restrict__ logw,
                                                    float* __restrict__ out_l) {
    int b = blockIdx.x;
    int tid = threadIdx.x;
    __shared__ int wcnt[TX_];
    __shared__ float partial[8];
    wcnt[tid] = 0;
    __syncthreads();
    for (int y = tid; y < TY_; y += 512)
        atomicAdd(&wcnt[path[b * TY_ + y]], 1);
    __syncthreads();
    float t = logw[b * TX_ + tid] - logf((float)wcnt[tid] + 1e-6f);
    float sq = t * t;
#pragma unroll
    for (int off = 32; off > 0; off >>= 1) sq += __shfl_down(sq, off);
    if ((tid & 63) == 0) partial[tid >> 6] = sq;
    __syncthreads();
    if (tid == 0) {
        float s = 0.f;
#pragma unroll
        for (int i = 0; i < 8; i++) s += partial[i];
        out_l[b] = s;
    }
}

// ============ Kernel F: gather out_main ============
__global__ __launch_bounds__(256) void gather_main(const int* __restrict__ path,
                                                   const float* __restrict__ xm,
                                                   const float* __restrict__ xl,
                                                   float* __restrict__ out) {
    int c = blockIdx.x;      // 0..383
    int b = blockIdx.y;      // 0..15
    int tid = threadIdx.x;
    const float* src = (c < D_) ? (xm + ((size_t)b * D_ + c) * TX_)
                                : (xl + ((size_t)b * D_ + (c - D_)) * TX_);
    const int* pb = path + b * TY_;
    float* ob = out + ((size_t)b * 2 * D_ + c) * TY_;
#pragma unroll
    for (int k = 0; k < 8; k++) {
        int y = tid + k * 256;
        ob[y] = src[pb[y]];
    }
}

// ============ Kernel G: write one-hot attn ============
__global__ __launch_bounds__(128) void write_attn(const int* __restrict__ path,
                                                  float* __restrict__ attn) {
    int blk = blockIdx.x;            // b*2048 + y
    int b = blk >> 11;
    int y = blk & 2047;
    int tid = threadIdx.x;           // covers x in [4*tid, 4*tid+4)
    int p = path[b * TY_ + y];
    float4 val = make_float4(0.f, 0.f, 0.f, 0.f);
    if ((p >> 2) == tid) {
        int r = p & 3;
        if (r == 0) val.x = 1.f;
        else if (r == 1) val.y = 1.f;
        else if (r == 2) val.z = 1.f;
        else val.w = 1.f;
    }
    ((float4*)attn)[((size_t)blk) * 128 + tid] = val;
}

extern "C" void kernel_launch(void* const* d_in, const int* in_sizes, int n_in,
                              void* d_out, int out_size, void* d_ws, size_t ws_size,
                              hipStream_t stream) {
    const float* x_mean = (const float*)d_in[0];
    const float* x_logs = (const float*)d_in[1];
    const float* z      = (const float*)d_in[2];
    const float* logw   = (const float*)d_in[3];
    float* out = (float*)d_out;

    char* ws = (char*)d_ws;
    float* S            = (float*)(ws + 0);
    float* MS           = (float*)(ws + 6291456);
    float* NC           = (float*)(ws + 12615680);
    unsigned char* dirs = (unsigned char*)(ws + 79724544);
    float* Cpart        = (float*)(ws + 79724544);   // aliases dirs; dead before mas_forward
    int* path           = (int*)(ws + 81821696);

    float* out_main = out;                 // [B,384,TY]
    float* out_l    = out + 12582912;      // [B]
    float* out_attn = out + 12582928;      // [B,TY,TX]

    precomp<<<dim3(B_, 6), dim3(512), 0, stream>>>(x_mean, x_logs, S, MS, Cpart);
    gemm_nc<<<dim3(4, 16, 16), dim3(256), 0, stream>>>(z, S, MS, Cpart, NC);
    mas_forward<<<dim3(B_), dim3(64), 0, stream>>>(NC, dirs);
    mas_backtrack<<<dim3(B_), dim3(64), 0, stream>>>((const unsigned*)dirs, path);
    durations_ll<<<dim3(B_), dim3(512), 0, stream>>>(path, logw, out_l);
    gather_main<<<dim3(384, 16), dim3(256), 0, stream>>>(path, x_mean, x_logs, out_main);
    write_attn<<<dim3(B_ * TY_), dim3(128), 0, stream>>>(path, out_attn);
}

// Round 3
// 734.073 us; speedup vs baseline: 1.4409x; 1.4409x over previous
//
#include <hip/hip_runtime.h>
#include <hip/hip_bf16.h>
#include <math.h>

#define B_   16
#define D_   192
#define TX_  512
#define TY_  2048
#define NEGV (-1e9f)

// -------- workspace layout (bytes) --------
// S    : B*D*TX f32   @ 0          (6,291,456)
// MS   : B*D*TX f32   @ 6291456    (6,291,456)
// NC   : B*TY*TX f32  @ 12615680   (67,108,864)
// dirs : B*2048*64 u8 @ 79724544   (2,097,152)   [aliased: Cpart B*6*TX f32 in
//         first 196,608 B — consumed by gemm_nc BEFORE mas_forward writes dirs]
// path : B*TY  i32    @ 81821696   (131,072)

// -------- output layout (f32 elements) --------
// out_main [B,384,TY] @ 0, l_length [B] @ 12582912, attn [B,TY,TX] @ 12582928

typedef __attribute__((address_space(1))) const float glob_f;
typedef __attribute__((address_space(3))) float       lds_f;
typedef float f32x4 __attribute__((ext_vector_type(4)));   // real clang vector: valid asm "v" operand

// ============ Kernel A: precompute S, MS, partial C (deterministic) ============
__global__ __launch_bounds__(512) void precomp(const float* __restrict__ xm,
                                               const float* __restrict__ xl,
                                               float* __restrict__ S,
                                               float* __restrict__ MS,
                                               float* __restrict__ Cpart) {
    int b = blockIdx.x;
    int p = blockIdx.y;
    int x = threadIdx.x;
    size_t base = ((size_t)b * D_ + p * 32) * TX_;
    const float* mb = xm + base;
    const float* lb = xl + base;
    float* Sb  = S  + base;
    float* MSb = MS + base;
    float c = 0.f;
    for (int d = 0; d < 32; d++) {
        float lg = lb[d * TX_ + x];
        float mn = mb[d * TX_ + x];
        float s  = expf(-2.f * lg);
        float ms = mn * s;
        Sb[d * TX_ + x]  = s;
        MSb[d * TX_ + x] = ms;
        c += -0.9189385332046727f - lg - 0.5f * mn * mn * s;   // nc1 + nc4 terms
    }
    Cpart[(b * 6 + p) * TX_ + x] = c;
}

// ============ Kernel B: NC = A(z)*B(s,ms) + c, f32 128x128 tile, 8x8 micro ============
// unroll 2 on kk: keeps live set ~160 VGPR (R3's full unroll spilled at 256).
__global__ __launch_bounds__(256) void gemm_nc(const float* __restrict__ z,
                                               const float* __restrict__ S,
                                               const float* __restrict__ MS,
                                               const float* __restrict__ Cpart,
                                               float* __restrict__ NC) {
    int bx = blockIdx.x;            // 4  -> x tiles of 128
    int by = blockIdx.y;            // 16 -> y tiles of 128
    int b  = blockIdx.z;            // 16
    int tid = threadIdx.x;
    int tx = tid & 15, ty = tid >> 4;
    __shared__ __align__(16) float Zt[16 * 128];
    __shared__ __align__(16) float St[16 * 128];
    __shared__ __align__(16) float MSt[16 * 128];

    float acc[8][8];
#pragma unroll
    for (int i = 0; i < 8; i++)
#pragma unroll
        for (int j = 0; j < 8; j++) acc[i][j] = 0.f;

    int x0 = bx * 128, y0 = by * 128;
    const float* zb  = z  + (size_t)b * D_ * TY_;
    const float* Sb  = S  + (size_t)b * D_ * TX_;
    const float* MSb = MS + (size_t)b * D_ * TX_;

    for (int k0 = 0; k0 < D_; k0 += 16) {
        // stage 3 x (16 rows x 128 cols) via async global->LDS, 16B per lane
#pragma unroll
        for (int j = 0; j < 2; j++) {
            int f = tid + j * 256;          // 0..511 float4 slots
            int kk = f >> 5, c = (f & 31) * 4;
            __builtin_amdgcn_global_load_lds((glob_f*)(zb  + (size_t)(k0 + kk) * TY_ + y0 + c),
                                             (lds_f*)(Zt  + f * 4), 16, 0, 0);
            __builtin_amdgcn_global_load_lds((glob_f*)(Sb  + (size_t)(k0 + kk) * TX_ + x0 + c),
                                             (lds_f*)(St  + f * 4), 16, 0, 0);
            __builtin_amdgcn_global_load_lds((glob_f*)(MSb + (size_t)(k0 + kk) * TX_ + x0 + c),
                                             (lds_f*)(MSt + f * 4), 16, 0, 0);
        }
        __syncthreads();

#pragma unroll 2
        for (int kk = 0; kk < 16; kk++) {
            float4 z0 = *(const float4*)&Zt[kk * 128 + ty * 4];
            float4 z1 = *(const float4*)&Zt[kk * 128 + 64 + ty * 4];
            float4 s0 = *(const float4*)&St[kk * 128 + tx * 4];
            float4 s1 = *(const float4*)&St[kk * 128 + 64 + tx * 4];
            float4 m0 = *(const float4*)&MSt[kk * 128 + tx * 4];
            float4 m1 = *(const float4*)&MSt[kk * 128 + 64 + tx * 4];
            float4 u0, u1;
            u0.x = -0.5f * z0.x * z0.x; u0.y = -0.5f * z0.y * z0.y;
            u0.z = -0.5f * z0.z * z0.z; u0.w = -0.5f * z0.w * z0.w;
            u1.x = -0.5f * z1.x * z1.x; u1.y = -0.5f * z1.y * z1.y;
            u1.z = -0.5f * z1.z * z1.z; u1.w = -0.5f * z1.w * z1.w;
            float zz[8] = {z0.x, z0.y, z0.z, z0.w, z1.x, z1.y, z1.z, z1.w};
            float uu[8] = {u0.x, u0.y, u0.z, u0.w, u1.x, u1.y, u1.z, u1.w};
            float ss[8] = {s0.x, s0.y, s0.z, s0.w, s1.x, s1.y, s1.z, s1.w};
            float mm[8] = {m0.x, m0.y, m0.z, m0.w, m1.x, m1.y, m1.z, m1.w};
#pragma unroll
            for (int i = 0; i < 8; i++)
#pragma unroll
                for (int j = 0; j < 8; j++)
                    acc[i][j] += uu[i] * ss[j] + zz[i] * mm[j];
        }
        __syncthreads();
    }

    // column constants: sum 6 deterministic partials
    float cv[8] = {0, 0, 0, 0, 0, 0, 0, 0};
#pragma unroll
    for (int p = 0; p < 6; p++) {
        float4 c0 = *(const float4*)&Cpart[(b * 6 + p) * TX_ + x0 + tx * 4];
        float4 c1 = *(const float4*)&Cpart[(b * 6 + p) * TX_ + x0 + 64 + tx * 4];
        cv[0] += c0.x; cv[1] += c0.y; cv[2] += c0.z; cv[3] += c0.w;
        cv[4] += c1.x; cv[5] += c1.y; cv[6] += c1.z; cv[7] += c1.w;
    }

#pragma unroll
    for (int i = 0; i < 8; i++) {
        int y = y0 + ty * 4 + (i & 3) + 64 * (i >> 2);
        float4 o0, o1;
        o0.x = acc[i][0] + cv[0]; o0.y = acc[i][1] + cv[1];
        o0.z = acc[i][2] + cv[2]; o0.w = acc[i][3] + cv[3];
        o1.x = acc[i][4] + cv[4]; o1.y = acc[i][5] + cv[5];
        o1.z = acc[i][6] + cv[6]; o1.w = acc[i][7] + cv[7];
        *(float4*)&NC[((size_t)b * TY_ + y) * TX_ + x0 + tx * 4]      = o0;
        *(float4*)&NC[((size_t)b * TY_ + y) * TX_ + x0 + 64 + tx * 4] = o1;
    }
}

// ============ Kernel C: MAS forward DP — asm register ring, counted vmcnt ============
// R7 (= R6 fixed): all vmcnt-counted ops are volatile inline asm in pinned
// program order — per row exactly {global_store_byte dirs(y), loadA(y+16),
// loadC(y+16)}. Loads for row y issue 16 phases early => at phase y's wait the
// newer-op count is 15*3=45 => s_waitcnt vmcnt(45) releases row y and keeps 15
// rows in flight (>= HBM latency). The wait TIES the consumed ring registers
// ("+v") so no compiler copy/use can touch the in-flight load destination
// before the wait; sched_barrier(0) after each wait per rule #18.
// R6's crash: HIP float4 is a C++ class -> invalid asm "v" operand; ring
// operands are now ext_vector f32x4.
__global__ __launch_bounds__(64, 1) void mas_forward(const float* __restrict__ NC,
                                                     unsigned char* __restrict__ dirs) {
    int b = blockIdx.x;
    int lane = threadIdx.x;
    const float* ncb = NC + (size_t)b * TY_ * TX_;
    int voff = lane * 32;                      // byte offset of this lane's 8 floats

    // nc[0,0]: compiler-tracked load; its waitcnt lands before the asm ring loads
    float nc00 = ncb[0];
    asm volatile("" :: "v"(nc00));

    float v[8];
#pragma unroll
    for (int j = 0; j < 8; j++) v[j] = NEGV;
    if (lane == 0) v[0] = nc00;

    float bound = NEGV;   // pending shfl result: lane-1's v[7] after previous row

    auto row_step = [&](f32x4 a, f32x4 c, int y, bool mask) -> unsigned {
        float ncv[8] = {a.x, a.y, a.z, a.w, c.x, c.y, c.z, c.w};
        float vd0 = (lane == 0) ? NEGV : bound;
        // element 7 first: compute, mask, and launch the cross-lane transfer
        float v6o = v[6], v7o = v[7];
        float v7n = ncv[7] + fmaxf(v7o, v6o);
        if (mask && y < 511 && lane * 8 + 7 > y) v7n = NEGV;
        bound = __shfl_up(v7n, 1);               // consumed at next row's vd0
        unsigned bits = (v6o > v7o) ? 0x80u : 0u;
        float vd = vd0;
#pragma unroll
        for (int j = 0; j < 7; j++) {
            float vp = v[j];
            bits |= (vd > vp) ? (1u << j) : 0u;
            v[j] = ncv[j] + fmaxf(vp, vd);
            vd = vp;
        }
        if (mask && y < 511) {
            int xb = lane * 8;
#pragma unroll
            for (int j = 0; j < 7; j++)
                if (xb + j > y) v[j] = NEGV;
        }
        v[7] = v7n;
        return bits;
    };

    f32x4 r0a, r0c, r1a, r1c, r2a, r2c, r3a, r3c, r4a, r4c, r5a, r5c, r6a, r6c, r7a, r7c;
    f32x4 r8a, r8c, r9a, r9c, r10a, r10c, r11a, r11c, r12a, r12c, r13a, r13c, r14a, r14c, r15a, r15c;

    const float* pf = ncb + TX_;                         // next row to load
    unsigned char* dp = dirs + (size_t)b * 2048 * 64;    // dirs row 0 base

#define LOADPAIR(RA, RC)                                                   \
    do {                                                                   \
        asm volatile("global_load_dwordx4 %0, %2, %1 offset:0"             \
                     : "=v"(RA) : "s"(pf), "v"(voff));                     \
        asm volatile("global_load_dwordx4 %0, %2, %1 offset:16"            \
                     : "=v"(RC) : "s"(pf), "v"(voff));                     \
        pf += TX_;                                                         \
    } while (0)

#define STOREBITS(BITS)                                                    \
    asm volatile("global_store_byte %1, %2, %0" :: "s"(dp), "v"(lane), "v"(BITS))

#define PHASE(RA, RC, MASKED)                                              \
    do {                                                                   \
        asm volatile("s_waitcnt vmcnt(45)" : "+v"(RA), "+v"(RC));          \
        __builtin_amdgcn_sched_barrier(0);                                 \
        unsigned bits_ = row_step(RA, RC, y, MASKED);                      \
        STOREBITS(bits_);                                                  \
        LOADPAIR(RA, RC);                                                  \
        dp += 64;                                                          \
        y++;                                                               \
    } while (0)

#define PH16(MASKED)                                                       \
    PHASE(r0a, r0c, MASKED);  PHASE(r1a, r1c, MASKED);                     \
    PHASE(r2a, r2c, MASKED);  PHASE(r3a, r3c, MASKED);                     \
    PHASE(r4a, r4c, MASKED);  PHASE(r5a, r5c, MASKED);                     \
    PHASE(r6a, r6c, MASKED);  PHASE(r7a, r7c, MASKED);                     \
    PHASE(r8a, r8c, MASKED);  PHASE(r9a, r9c, MASKED);                     \
    PHASE(r10a, r10c, MASKED); PHASE(r11a, r11c, MASKED);                  \
    PHASE(r12a, r12c, MASKED); PHASE(r13a, r13c, MASKED);                  \
    PHASE(r14a, r14c, MASKED); PHASE(r15a, r15c, MASKED);

    // prologue: rows 1..16 into ring slots 0..15, then drain once
    LOADPAIR(r0a, r0c);   LOADPAIR(r1a, r1c);   LOADPAIR(r2a, r2c);   LOADPAIR(r3a, r3c);
    LOADPAIR(r4a, r4c);   LOADPAIR(r5a, r5c);   LOADPAIR(r6a, r6c);   LOADPAIR(r7a, r7c);
    LOADPAIR(r8a, r8c);   LOADPAIR(r9a, r9c);   LOADPAIR(r10a, r10c); LOADPAIR(r11a, r11c);
    LOADPAIR(r12a, r12c); LOADPAIR(r13a, r13c); LOADPAIR(r14a, r14c); LOADPAIR(r15a, r15c);
    asm volatile("s_waitcnt vmcnt(0)" ::: "memory");
    __builtin_amdgcn_sched_barrier(0);

    int y = 1;
    // masked phase: rows 1..512 (mask condition y<511 applied inside)
    for (int t = 0; t < 32; t++) {
        PH16(true)
    }
    // unmasked phase: rows 513..2016
    for (int t = 32; t < 126; t++) {
        PH16(false)
    }
    // rows 2017..2031 with prefetch (loads rows 2033..2047)
    PHASE(r0a, r0c, false);  PHASE(r1a, r1c, false);
    PHASE(r2a, r2c, false);  PHASE(r3a, r3c, false);
    PHASE(r4a, r4c, false);  PHASE(r5a, r5c, false);
    PHASE(r6a, r6c, false);  PHASE(r7a, r7c, false);
    PHASE(r8a, r8c, false);  PHASE(r9a, r9c, false);
    PHASE(r10a, r10c, false); PHASE(r11a, r11c, false);
    PHASE(r12a, r12c, false); PHASE(r13a, r13c, false);
    PHASE(r14a, r14c, false);
    // row 2032: wait(45) exactly releases its loads; no further prefetch
    {
        asm volatile("s_waitcnt vmcnt(45)" : "+v"(r15a), "+v"(r15c));
        __builtin_amdgcn_sched_barrier(0);
        unsigned bits_ = row_step(r15a, r15c, y, false);
        STOREBITS(bits_);
        dp += 64;
        y++;
    }

    // epilogue: rows 2033..2047 from ring slots 0..14. vmcnt(1): newest op is
    // the row-2032 store; all ring loads (older) are complete after this.
    asm volatile("s_waitcnt vmcnt(1)"
                 : "+v"(r0a), "+v"(r0c), "+v"(r1a), "+v"(r1c),
                   "+v"(r2a), "+v"(r2c), "+v"(r3a), "+v"(r3c),
                   "+v"(r4a), "+v"(r4c), "+v"(r5a), "+v"(r5c),
                   "+v"(r6a), "+v"(r6c), "+v"(r7a), "+v"(r7c));
    asm volatile("s_waitcnt vmcnt(1)"
                 : "+v"(r8a), "+v"(r8c), "+v"(r9a), "+v"(r9c),
                   "+v"(r10a), "+v"(r10c), "+v"(r11a), "+v"(r11c),
                   "+v"(r12a), "+v"(r12c), "+v"(r13a), "+v"(r13c),
                   "+v"(r14a), "+v"(r14c));
    __builtin_amdgcn_sched_barrier(0);
    {
        unsigned bb;
        bb = row_step(r0a, r0c, y, false);  STOREBITS(bb); dp += 64; y++;
        bb = row_step(r1a, r1c, y, false);  STOREBITS(bb); dp += 64; y++;
        bb = row_step(r2a, r2c, y, false);  STOREBITS(bb); dp += 64; y++;
        bb = row_step(r3a, r3c, y, false);  STOREBITS(bb); dp += 64; y++;
        bb = row_step(r4a, r4c, y, false);  STOREBITS(bb); dp += 64; y++;
        bb = row_step(r5a, r5c, y, false);  STOREBITS(bb); dp += 64; y++;
        bb = row_step(r6a, r6c, y, false);  STOREBITS(bb); dp += 64; y++;
        bb = row_step(r7a, r7c, y, false);  STOREBITS(bb); dp += 64; y++;
        bb = row_step(r8a, r8c, y, false);  STOREBITS(bb); dp += 64; y++;
        bb = row_step(r9a, r9c, y, false);  STOREBITS(bb); dp += 64; y++;
        bb = row_step(r10a, r10c, y, false); STOREBITS(bb); dp += 64; y++;
        bb = row_step(r11a, r11c, y, false); STOREBITS(bb); dp += 64; y++;
        bb = row_step(r12a, r12c, y, false); STOREBITS(bb); dp += 64; y++;
        bb = row_step(r13a, r13c, y, false); STOREBITS(bb); dp += 64; y++;
        bb = row_step(r14a, r14c, y, false); STOREBITS(bb);
    }

#undef PH16
#undef PHASE
#undef STOREBITS
#undef LOADPAIR
}

// ============ Kernel D: backtrack (one wave per sample, shfl-windowed) ============
__global__ __launch_bounds__(64, 1) void mas_backtrack(const unsigned* __restrict__ dirs,
                                                       int* __restrict__ path) {
    int b = blockIdx.x;
    int lane = threadIdx.x;
    const unsigned* db = dirs + (size_t)b * 2048 * 16;   // 16 dwords per row
    int idx = TX_ - 1;                                   // path[2047]

    for (int y_hi = 2047; y_hi >= 1; y_hi -= 64) {
        int wb = (idx >> 5) - 2;
        if (wb < 0) wb = 0;
        if (wb > 13) wb = 13;                            // clamp: garbage-proof
        int base = wb << 5;
        int y = y_hi - lane;
        unsigned w0 = 0, w1 = 0, w2 = 0;
        if (y >= 1) {
            const unsigned* r = db + (size_t)(y - 1) * 16 + wb;
            w0 = r[0]; w1 = r[1]; w2 = r[2];
        }
        int steps = (y_hi < 64) ? y_hi : 64;
        int my_path = 0;
#pragma unroll 8
        for (int t = 0; t < steps; t++) {
            if (lane == t) my_path = idx;
            unsigned u0 = (unsigned)__shfl((int)w0, t);
            unsigned u1 = (unsigned)__shfl((int)w1, t);
            unsigned u2 = (unsigned)__shfl((int)w2, t);
            int off = idx - base;
            unsigned w = (off < 32) ? u0 : ((off < 64) ? u1 : u2);
            idx -= (int)((w >> (off & 31)) & 1u);
        }
        if (lane < steps) path[b * TY_ + (y_hi - lane)] = my_path;
    }
    if (lane == 0) path[b * TY_ + 0] = idx;
}

// ============ Kernel E: durations + l_length ============
__global__ __launch_bounds__(512) void durations_ll(const int* __restrict__ path,
                                                    const float* __restrict__ logw,
                                                    float* __restrict__ out_l) {
    int b = blockIdx.x;
    int tid = threadIdx.x;
    __shared__ int wcnt[TX_];
    __shared__ float partial[8];
    wcnt[tid] = 0;
    __syncthreads();
    for (int y = tid; y < TY_; y += 512) {
        int p = path[b * TY_ + y];
        if ((unsigned)p > 511u) p = 0;                   // clamp: garbage-proof
        atomicAdd(&wcnt[p], 1);
    }
    __syncthreads();
    float t = logw[b * TX_ + tid] - logf((float)wcnt[tid] + 1e-6f);
    float sq = t * t;
#pragma unroll
    for (int off = 32; off > 0; off >>= 1) sq += __shfl_down(sq, off);
    if ((tid & 63) == 0) partial[tid >> 6] = sq;
    __syncthreads();
    if (tid == 0) {
        float s = 0.f;
#pragma unroll
        for (int i = 0; i < 8; i++) s += partial[i];
        out_l[b] = s;
    }
}

// ============ Kernel F: gather out_main ============
__global__ __launch_bounds__(256) void gather_main(const int* __restrict__ path,
                                                   const float* __restrict__ xm,
                                                   const float* __restrict__ xl,
                                                   float* __restrict__ out) {
    int c = blockIdx.x;      // 0..383
    int b = blockIdx.y;      // 0..15
    int tid = threadIdx.x;
    const float* src = (c < D_) ? (xm + ((size_t)b * D_ + c) * TX_)
                                : (xl + ((size_t)b * D_ + (c - D_)) * TX_);
    const int* pb = path + b * TY_;
    float* ob = out + ((size_t)b * 2 * D_ + c) * TY_;
#pragma unroll
    for (int k = 0; k < 8; k++) {
        int y = tid + k * 256;
        int p = pb[y];
        if ((unsigned)p > 511u) p = 0;                   // clamp: garbage-proof
        ob[y] = src[p];
    }
}

// ============ Kernel G: write one-hot attn ============
__global__ __launch_bounds__(128) void write_attn(const int* __restrict__ path,
                                                  float* __restrict__ attn) {
    int blk = blockIdx.x;            // b*2048 + y
    int b = blk >> 11;
    int y = blk & 2047;
    int tid = threadIdx.x;           // covers x in [4*tid, 4*tid+4)
    int p = path[b * TY_ + y];
    float4 val = make_float4(0.f, 0.f, 0.f, 0.f);
    if ((p >> 2) == tid) {
        int r = p & 3;
        if (r == 0) val.x = 1.f;
        else if (r == 1) val.y = 1.f;
        else if (r == 2) val.z = 1.f;
        else val.w = 1.f;
    }
    ((float4*)attn)[((size_t)blk) * 128 + tid] = val;
}

extern "C" void kernel_launch(void* const* d_in, const int* in_sizes, int n_in,
                              void* d_out, int out_size, void* d_ws, size_t ws_size,
                              hipStream_t stream) {
    const float* x_mean = (const float*)d_in[0];
    const float* x_logs = (const float*)d_in[1];
    const float* z      = (const float*)d_in[2];
    const float* logw   = (const float*)d_in[3];
    float* out = (float*)d_out;

    char* ws = (char*)d_ws;
    float* S            = (float*)(ws + 0);
    float* MS           = (float*)(ws + 6291456);
    float* NC           = (float*)(ws + 12615680);
    unsigned char* dirs = (unsigned char*)(ws + 79724544);
    float* Cpart        = (float*)(ws + 79724544);   // aliases dirs; dead before mas_forward
    int* path           = (int*)(ws + 81821696);

    float* out_main = out;                 // [B,384,TY]
    float* out_l    = out + 12582912;      // [B]
    float* out_attn = out + 12582928;      // [B,TY,TX]

    precomp<<<dim3(B_, 6), dim3(512), 0, stream>>>(x_mean, x_logs, S, MS, Cpart);
    gemm_nc<<<dim3(4, 16, 16), dim3(256), 0, stream>>>(z, S, MS, Cpart, NC);
    mas_forward<<<dim3(B_), dim3(64), 0, stream>>>(NC, dirs);
    mas_backtrack<<<dim3(B_), dim3(64), 0, stream>>>((const unsigned*)dirs, path);
    durations_ll<<<dim3(B_), dim3(512), 0, stream>>>(path, logw, out_l);
    gather_main<<<dim3(384, 16), dim3(256), 0, stream>>>(path, x_mean, x_logs, out_main);
    write_attn<<<dim3(B_ * TY_), dim3(128), 0, stream>>>(path, out_attn);
}

// Round 7
// 717.090 us; speedup vs baseline: 1.4751x; 1.0237x over previous
//
#include <hip/hip_runtime.h>
#include <hip/hip_bf16.h>
#include <math.h>

#define B_   16
#define D_   192
#define TX_  512
#define TY_  2048
#define NEGV (-1e9f)

// -------- workspace layout (bytes) --------
// S    : B*D*TX f32   @ 0          (6,291,456)
// MS   : B*D*TX f32   @ 6291456    (6,291,456)
// NC   : B*TY*TX f32  @ 12615680   (67,108,864)
// dirs : B*2048*64 u8 @ 79724544   (2,097,152)   [aliased: Cpart B*6*TX f32 in
//         first 196,608 B — consumed by gemm_nc BEFORE mas_forward writes dirs]
// path : B*TY  i32    @ 81821696   (131,072)

// -------- output layout (f32 elements) --------
// out_main [B,384,TY] @ 0, l_length [B] @ 12582912, attn [B,TY,TX] @ 12582928

typedef __attribute__((address_space(1))) const float glob_f;
typedef __attribute__((address_space(3))) float       lds_f;
typedef float f32x4 __attribute__((ext_vector_type(4)));   // real clang vector: valid asm "v" operand

// ============ Kernel A: precompute S, MS, partial C (deterministic) ============
__global__ __launch_bounds__(512) void precomp(const float* __restrict__ xm,
                                               const float* __restrict__ xl,
                                               float* __restrict__ S,
                                               float* __restrict__ MS,
                                               float* __restrict__ Cpart) {
    int b = blockIdx.x;
    int p = blockIdx.y;
    int x = threadIdx.x;
    size_t base = ((size_t)b * D_ + p * 32) * TX_;
    const float* mb = xm + base;
    const float* lb = xl + base;
    float* Sb  = S  + base;
    float* MSb = MS + base;
    float c = 0.f;
    for (int d = 0; d < 32; d++) {
        float lg = lb[d * TX_ + x];
        float mn = mb[d * TX_ + x];
        float s  = expf(-2.f * lg);
        float ms = mn * s;
        Sb[d * TX_ + x]  = s;
        MSb[d * TX_ + x] = ms;
        c += -0.9189385332046727f - lg - 0.5f * mn * mn * s;   // nc1 + nc4 terms
    }
    Cpart[(b * 6 + p) * TX_ + x] = c;
}

// ============ Kernel B: NC = A(z)*B(s,ms) + c, f32 128x128 tile, 8x8 micro ============
__global__ __launch_bounds__(256) void gemm_nc(const float* __restrict__ z,
                                               const float* __restrict__ S,
                                               const float* __restrict__ MS,
                                               const float* __restrict__ Cpart,
                                               float* __restrict__ NC) {
    int bx = blockIdx.x;            // 4  -> x tiles of 128
    int by = blockIdx.y;            // 16 -> y tiles of 128
    int b  = blockIdx.z;            // 16
    int tid = threadIdx.x;
    int tx = tid & 15, ty = tid >> 4;
    __shared__ __align__(16) float Zt[16 * 128];
    __shared__ __align__(16) float St[16 * 128];
    __shared__ __align__(16) float MSt[16 * 128];

    float acc[8][8];
#pragma unroll
    for (int i = 0; i < 8; i++)
#pragma unroll
        for (int j = 0; j < 8; j++) acc[i][j] = 0.f;

    int x0 = bx * 128, y0 = by * 128;
    const float* zb  = z  + (size_t)b * D_ * TY_;
    const float* Sb  = S  + (size_t)b * D_ * TX_;
    const float* MSb = MS + (size_t)b * D_ * TX_;

    for (int k0 = 0; k0 < D_; k0 += 16) {
        // stage 3 x (16 rows x 128 cols) via async global->LDS, 16B per lane
#pragma unroll
        for (int j = 0; j < 2; j++) {
            int f = tid + j * 256;          // 0..511 float4 slots
            int kk = f >> 5, c = (f & 31) * 4;
            __builtin_amdgcn_global_load_lds((glob_f*)(zb  + (size_t)(k0 + kk) * TY_ + y0 + c),
                                             (lds_f*)(Zt  + f * 4), 16, 0, 0);
            __builtin_amdgcn_global_load_lds((glob_f*)(Sb  + (size_t)(k0 + kk) * TX_ + x0 + c),
                                             (lds_f*)(St  + f * 4), 16, 0, 0);
            __builtin_amdgcn_global_load_lds((glob_f*)(MSb + (size_t)(k0 + kk) * TX_ + x0 + c),
                                             (lds_f*)(MSt + f * 4), 16, 0, 0);
        }
        __syncthreads();

#pragma unroll 2
        for (int kk = 0; kk < 16; kk++) {
            float4 z0 = *(const float4*)&Zt[kk * 128 + ty * 4];
            float4 z1 = *(const float4*)&Zt[kk * 128 + 64 + ty * 4];
            float4 s0 = *(const float4*)&St[kk * 128 + tx * 4];
            float4 s1 = *(const float4*)&St[kk * 128 + 64 + tx * 4];
            float4 m0 = *(const float4*)&MSt[kk * 128 + tx * 4];
            float4 m1 = *(const float4*)&MSt[kk * 128 + 64 + tx * 4];
            float4 u0, u1;
            u0.x = -0.5f * z0.x * z0.x; u0.y = -0.5f * z0.y * z0.y;
            u0.z = -0.5f * z0.z * z0.z; u0.w = -0.5f * z0.w * z0.w;
            u1.x = -0.5f * z1.x * z1.x; u1.y = -0.5f * z1.y * z1.y;
            u1.z = -0.5f * z1.z * z1.z; u1.w = -0.5f * z1.w * z1.w;
            float zz[8] = {z0.x, z0.y, z0.z, z0.w, z1.x, z1.y, z1.z, z1.w};
            float uu[8] = {u0.x, u0.y, u0.z, u0.w, u1.x, u1.y, u1.z, u1.w};
            float ss[8] = {s0.x, s0.y, s0.z, s0.w, s1.x, s1.y, s1.z, s1.w};
            float mm[8] = {m0.x, m0.y, m0.z, m0.w, m1.x, m1.y, m1.z, m1.w};
#pragma unroll
            for (int i = 0; i < 8; i++)
#pragma unroll
                for (int j = 0; j < 8; j++)
                    acc[i][j] += uu[i] * ss[j] + zz[i] * mm[j];
        }
        __syncthreads();
    }

    // column constants: sum 6 deterministic partials
    float cv[8] = {0, 0, 0, 0, 0, 0, 0, 0};
#pragma unroll
    for (int p = 0; p < 6; p++) {
        float4 c0 = *(const float4*)&Cpart[(b * 6 + p) * TX_ + x0 + tx * 4];
        float4 c1 = *(const float4*)&Cpart[(b * 6 + p) * TX_ + x0 + 64 + tx * 4];
        cv[0] += c0.x; cv[1] += c0.y; cv[2] += c0.z; cv[3] += c0.w;
        cv[4] += c1.x; cv[5] += c1.y; cv[6] += c1.z; cv[7] += c1.w;
    }

#pragma unroll
    for (int i = 0; i < 8; i++) {
        int y = y0 + ty * 4 + (i & 3) + 64 * (i >> 2);
        float4 o0, o1;
        o0.x = acc[i][0] + cv[0]; o0.y = acc[i][1] + cv[1];
        o0.z = acc[i][2] + cv[2]; o0.w = acc[i][3] + cv[3];
        o1.x = acc[i][4] + cv[4]; o1.y = acc[i][5] + cv[5];
        o1.z = acc[i][6] + cv[6]; o1.w = acc[i][7] + cv[7];
        *(float4*)&NC[((size_t)b * TY_ + y) * TX_ + x0 + tx * 4]      = o0;
        *(float4*)&NC[((size_t)b * TY_ + y) * TX_ + x0 + 64 + tx * 4] = o1;
    }
}

// ============ Kernel C: MAS forward DP — asm register ring + DPP boundary ============
// R11 = R3 (verified passing, 249us) + ONE change: the per-row cross-lane
// boundary move (lane l-1's v[7] -> lane l) uses DPP wf_sr1 (pure VALU,
// ~8cy) instead of __shfl_up (DS-pipe round trip, ~120cy single-outstanding).
// Rationale: R0 (no prefetch) = 308 cy/row vs R3 (full 16-row prefetch) =
// 292 cy/row -> loads were never the bottleneck; the common per-row serial
// cost is the shfl's DS latency (VALU issue is only ~38cy/row from
// VALUBusy=0.81% over 16 active CUs). Lane 0 ignores `bound` via the
// explicit (lane==0)?NEGV select (already in R3), so DPP edge/bound_ctrl
// semantics are dead code. The 2-wave skew arc (R8-R10) is abandoned:
// 3 rounds of nondeterministic seam corruption, negative EV to keep hunting.
// All vmcnt-counted ops are volatile inline asm in pinned program order —
// per row exactly {global_store_byte dirs(y), loadA(y+16), loadC(y+16)}.
// Loads for row y issue 16 phases early => at phase y's wait the newer-op
// count is 15*3=45 => s_waitcnt vmcnt(45) releases row y and keeps 15 rows
// in flight. The wait TIES the consumed ring registers ("+v").
__global__ __launch_bounds__(64, 1) void mas_forward(const float* __restrict__ NC,
                                                     unsigned char* __restrict__ dirs) {
    int b = blockIdx.x;
    int lane = threadIdx.x;
    const float* ncb = NC + (size_t)b * TY_ * TX_;
    int voff = lane * 32;                      // byte offset of this lane's 8 floats

    // nc[0,0]: compiler-tracked load; its waitcnt lands before the asm ring loads
    float nc00 = ncb[0];
    asm volatile("" :: "v"(nc00));

    float v[8];
#pragma unroll
    for (int j = 0; j < 8; j++) v[j] = NEGV;
    if (lane == 0) v[0] = nc00;

    float bound = NEGV;   // lane-1's v[7] after previous row (via DPP)
    int negi = __float_as_int(NEGV);

    auto row_step = [&](f32x4 a, f32x4 c, int y, bool mask) -> unsigned {
        float ncv[8] = {a.x, a.y, a.z, a.w, c.x, c.y, c.z, c.w};
        float vd0 = (lane == 0) ? NEGV : bound;
        // element 7 first: compute, mask, and launch the cross-lane transfer
        float v6o = v[6], v7o = v[7];
        float v7n = ncv[7] + fmaxf(v7o, v6o);
        if (mask && y < 511 && lane * 8 + 7 > y) v7n = NEGV;
        // DPP wf_sr1: lane l <- lane l-1's v7n. Pure VALU; replaces the
        // __shfl_up DS round trip that dominated per-row latency.
        bound = __int_as_float(__builtin_amdgcn_update_dpp(
            negi, __float_as_int(v7n), 0x138, 0xf, 0xf, false));
        unsigned bits = (v6o > v7o) ? 0x80u : 0u;
        float vd = vd0;
#pragma unroll
        for (int j = 0; j < 7; j++) {
            float vp = v[j];
            bits |= (vd > vp) ? (1u << j) : 0u;
            v[j] = ncv[j] + fmaxf(vp, vd);
            vd = vp;
        }
        if (mask && y < 511) {
            int xb = lane * 8;
#pragma unroll
            for (int j = 0; j < 7; j++)
                if (xb + j > y) v[j] = NEGV;
        }
        v[7] = v7n;
        return bits;
    };

    f32x4 r0a, r0c, r1a, r1c, r2a, r2c, r3a, r3c, r4a, r4c, r5a, r5c, r6a, r6c, r7a, r7c;
    f32x4 r8a, r8c, r9a, r9c, r10a, r10c, r11a, r11c, r12a, r12c, r13a, r13c, r14a, r14c, r15a, r15c;

    const float* pf = ncb + TX_;                         // next row to load
    unsigned char* dp = dirs + (size_t)b * 2048 * 64;    // dirs row 0 base

#define LOADPAIR(RA, RC)                                                   \
    do {                                                                   \
        asm volatile("global_load_dwordx4 %0, %2, %1 offset:0"             \
                     : "=v"(RA) : "s"(pf), "v"(voff));                     \
        asm volatile("global_load_dwordx4 %0, %2, %1 offset:16"            \
                     : "=v"(RC) : "s"(pf), "v"(voff));                     \
        pf += TX_;                                                         \
    } while (0)

#define STOREBITS(BITS)                                                    \
    asm volatile("global_store_byte %1, %2, %0" :: "s"(dp), "v"(lane), "v"(BITS))

#define PHASE(RA, RC, MASKED)                                              \
    do {                                                                   \
        asm volatile("s_waitcnt vmcnt(45)" : "+v"(RA), "+v"(RC));          \
        __builtin_amdgcn_sched_barrier(0);                                 \
        unsigned bits_ = row_step(RA, RC, y, MASKED);                      \
        STOREBITS(bits_);                                                  \
        LOADPAIR(RA, RC);                                                  \
        dp += 64;                                                          \
        y++;                                                               \
    } while (0)

#define PH16(MASKED)                                                       \
    PHASE(r0a, r0c, MASKED);  PHASE(r1a, r1c, MASKED);                     \
    PHASE(r2a, r2c, MASKED);  PHASE(r3a, r3c, MASKED);                     \
    PHASE(r4a, r4c, MASKED);  PHASE(r5a, r5c, MASKED);                     \
    PHASE(r6a, r6c, MASKED);  PHASE(r7a, r7c, MASKED);                     \
    PHASE(r8a, r8c, MASKED);  PHASE(r9a, r9c, MASKED);                     \
    PHASE(r10a, r10c, MASKED); PHASE(r11a, r11c, MASKED);                  \
    PHASE(r12a, r12c, MASKED); PHASE(r13a, r13c, MASKED);                  \
    PHASE(r14a, r14c, MASKED); PHASE(r15a, r15c, MASKED);

    // prologue: rows 1..16 into ring slots 0..15, then drain once
    LOADPAIR(r0a, r0c);   LOADPAIR(r1a, r1c);   LOADPAIR(r2a, r2c);   LOADPAIR(r3a, r3c);
    LOADPAIR(r4a, r4c);   LOADPAIR(r5a, r5c);   LOADPAIR(r6a, r6c);   LOADPAIR(r7a, r7c);
    LOADPAIR(r8a, r8c);   LOADPAIR(r9a, r9c);   LOADPAIR(r10a, r10c); LOADPAIR(r11a, r11c);
    LOADPAIR(r12a, r12c); LOADPAIR(r13a, r13c); LOADPAIR(r14a, r14c); LOADPAIR(r15a, r15c);
    asm volatile("s_waitcnt vmcnt(0)" ::: "memory");
    __builtin_amdgcn_sched_barrier(0);

    int y = 1;
    // masked phase: rows 1..512 (mask condition y<511 applied inside)
    for (int t = 0; t < 32; t++) {
        PH16(true)
    }
    // unmasked phase: rows 513..2016
    for (int t = 32; t < 126; t++) {
        PH16(false)
    }
    // rows 2017..2031 with prefetch (loads rows 2033..2047)
    PHASE(r0a, r0c, false);  PHASE(r1a, r1c, false);
    PHASE(r2a, r2c, false);  PHASE(r3a, r3c, false);
    PHASE(r4a, r4c, false);  PHASE(r5a, r5c, false);
    PHASE(r6a, r6c, false);  PHASE(r7a, r7c, false);
    PHASE(r8a, r8c, false);  PHASE(r9a, r9c, false);
    PHASE(r10a, r10c, false); PHASE(r11a, r11c, false);
    PHASE(r12a, r12c, false); PHASE(r13a, r13c, false);
    PHASE(r14a, r14c, false);
    // row 2032: wait(45) exactly releases its loads; no further prefetch
    {
        asm volatile("s_waitcnt vmcnt(45)" : "+v"(r15a), "+v"(r15c));
        __builtin_amdgcn_sched_barrier(0);
        unsigned bits_ = row_step(r15a, r15c, y, false);
        STOREBITS(bits_);
        dp += 64;
        y++;
    }

    // epilogue: rows 2033..2047 from ring slots 0..14. vmcnt(1): newest op is
    // the row-2032 store; all ring loads (older) are complete after this.
    asm volatile("s_waitcnt vmcnt(1)"
                 : "+v"(r0a), "+v"(r0c), "+v"(r1a), "+v"(r1c),
                   "+v"(r2a), "+v"(r2c), "+v"(r3a), "+v"(r3c),
                   "+v"(r4a), "+v"(r4c), "+v"(r5a), "+v"(r5c),
                   "+v"(r6a), "+v"(r6c), "+v"(r7a), "+v"(r7c));
    asm volatile("s_waitcnt vmcnt(1)"
                 : "+v"(r8a), "+v"(r8c), "+v"(r9a), "+v"(r9c),
                   "+v"(r10a), "+v"(r10c), "+v"(r11a), "+v"(r11c),
                   "+v"(r12a), "+v"(r12c), "+v"(r13a), "+v"(r13c),
                   "+v"(r14a), "+v"(r14c));
    __builtin_amdgcn_sched_barrier(0);
    {
        unsigned bb;
        bb = row_step(r0a, r0c, y, false);  STOREBITS(bb); dp += 64; y++;
        bb = row_step(r1a, r1c, y, false);  STOREBITS(bb); dp += 64; y++;
        bb = row_step(r2a, r2c, y, false);  STOREBITS(bb); dp += 64; y++;
        bb = row_step(r3a, r3c, y, false);  STOREBITS(bb); dp += 64; y++;
        bb = row_step(r4a, r4c, y, false);  STOREBITS(bb); dp += 64; y++;
        bb = row_step(r5a, r5c, y, false);  STOREBITS(bb); dp += 64; y++;
        bb = row_step(r6a, r6c, y, false);  STOREBITS(bb); dp += 64; y++;
        bb = row_step(r7a, r7c, y, false);  STOREBITS(bb); dp += 64; y++;
        bb = row_step(r8a, r8c, y, false);  STOREBITS(bb); dp += 64; y++;
        bb = row_step(r9a, r9c, y, false);  STOREBITS(bb); dp += 64; y++;
        bb = row_step(r10a, r10c, y, false); STOREBITS(bb); dp += 64; y++;
        bb = row_step(r11a, r11c, y, false); STOREBITS(bb); dp += 64; y++;
        bb = row_step(r12a, r12c, y, false); STOREBITS(bb); dp += 64; y++;
        bb = row_step(r13a, r13c, y, false); STOREBITS(bb); dp += 64; y++;
        bb = row_step(r14a, r14c, y, false); STOREBITS(bb);
    }

#undef PH16
#undef PHASE
#undef STOREBITS
#undef LOADPAIR
}

// ============ Kernel D: backtrack (one wave per sample, shfl-windowed) ============
__global__ __launch_bounds__(64, 1) void mas_backtrack(const unsigned* __restrict__ dirs,
                                                       int* __restrict__ path) {
    int b = blockIdx.x;
    int lane = threadIdx.x;
    const unsigned* db = dirs + (size_t)b * 2048 * 16;   // 16 dwords per row
    int idx = TX_ - 1;                                   // path[2047]

    for (int y_hi = 2047; y_hi >= 1; y_hi -= 64) {
        int wb = (idx >> 5) - 2;
        if (wb < 0) wb = 0;
        if (wb > 13) wb = 13;                            // clamp: garbage-proof
        int base = wb << 5;
        int y = y_hi - lane;
        unsigned w0 = 0, w1 = 0, w2 = 0;
        if (y >= 1) {
            const unsigned* r = db + (size_t)(y - 1) * 16 + wb;
            w0 = r[0]; w1 = r[1]; w2 = r[2];
        }
        int steps = (y_hi < 64) ? y_hi : 64;
        int my_path = 0;
#pragma unroll 8
        for (int t = 0; t < steps; t++) {
            if (lane == t) my_path = idx;
            unsigned u0 = (unsigned)__shfl((int)w0, t);
            unsigned u1 = (unsigned)__shfl((int)w1, t);
            unsigned u2 = (unsigned)__shfl((int)w2, t);
            int off = idx - base;
            unsigned w = (off < 32) ? u0 : ((off < 64) ? u1 : u2);
            idx -= (int)((w >> (off & 31)) & 1u);
        }
        if (lane < steps) path[b * TY_ + (y_hi - lane)] = my_path;
    }
    if (lane == 0) path[b * TY_ + 0] = idx;
}

// ============ Kernel E: durations + l_length ============
__global__ __launch_bounds__(512) void durations_ll(const int* __restrict__ path,
                                                    const float* __restrict__ logw,
                                                    float* __restrict__ out_l) {
    int b = blockIdx.x;
    int tid = threadIdx.x;
    __shared__ int wcnt[TX_];
    __shared__ float partial[8];
    wcnt[tid] = 0;
    __syncthreads();
    for (int y = tid; y < TY_; y += 512) {
        int p = path[b * TY_ + y];
        if ((unsigned)p > 511u) p = 0;                   // clamp: garbage-proof
        atomicAdd(&wcnt[p], 1);
    }
    __syncthreads();
    float t = logw[b * TX_ + tid] - logf((float)wcnt[tid] + 1e-6f);
    float sq = t * t;
#pragma unroll
    for (int off = 32; off > 0; off >>= 1) sq += __shfl_down(sq, off);
    if ((tid & 63) == 0) partial[tid >> 6] = sq;
    __syncthreads();
    if (tid == 0) {
        float s = 0.f;
#pragma unroll
        for (int i = 0; i < 8; i++) s += partial[i];
        out_l[b] = s;
    }
}

// ============ Kernel F: gather out_main ============
__global__ __launch_bounds__(256) void gather_main(const int* __restrict__ path,
                                                   const float* __restrict__ xm,
                                                   const float* __restrict__ xl,
                                                   float* __restrict__ out) {
    int c = blockIdx.x;      // 0..383
    int b = blockIdx.y;      // 0..15
    int tid = threadIdx.x;
    const float* src = (c < D_) ? (xm + ((size_t)b * D_ + c) * TX_)
                                : (xl + ((size_t)b * D_ + (c - D_)) * TX_);
    const int* pb = path + b * TY_;
    float* ob = out + ((size_t)b * 2 * D_ + c) * TY_;
#pragma unroll
    for (int k = 0; k < 8; k++) {
        int y = tid + k * 256;
        int p = pb[y];
        if ((unsigned)p > 511u) p = 0;                   // clamp: garbage-proof
        ob[y] = src[p];
    }
}

// ============ Kernel G: write one-hot attn ============
__global__ __launch_bounds__(128) void write_attn(const int* __restrict__ path,
                                                  float* __restrict__ attn) {
    int blk = blockIdx.x;            // b*2048 + y
    int b = blk >> 11;
    int y = blk & 2047;
    int tid = threadIdx.x;           // covers x in [4*tid, 4*tid+4)
    int p = path[b * TY_ + y];
    float4 val = make_float4(0.f, 0.f, 0.f, 0.f);
    if ((p >> 2) == tid) {
        int r = p & 3;
        if (r == 0) val.x = 1.f;
        else if (r == 1) val.y = 1.f;
        else if (r == 2) val.z = 1.f;
        else val.w = 1.f;
    }
    ((float4*)attn)[((size_t)blk) * 128 + tid] = val;
}

extern "C" void kernel_launch(void* const* d_in, const int* in_sizes, int n_in,
                              void* d_out, int out_size, void* d_ws, size_t ws_size,
                              hipStream_t stream) {
    const float* x_mean = (const float*)d_in[0];
    const float* x_logs = (const float*)d_in[1];
    const float* z      = (const float*)d_in[2];
    const float* logw   = (const float*)d_in[3];
    float* out = (float*)d_out;

    char* ws = (char*)d_ws;
    float* S            = (float*)(ws + 0);
    float* MS           = (float*)(ws + 6291456);
    float* NC           = (float*)(ws + 12615680);
    unsigned char* dirs = (unsigned char*)(ws + 79724544);
    float* Cpart        = (float*)(ws + 79724544);   // aliases dirs; dead before mas_forward
    int* path           = (int*)(ws + 81821696);

    float* out_main = out;                 // [B,384,TY]
    float* out_l    = out + 12582912;      // [B]
    float* out_attn = out + 12582928;      // [B,TY,TX]

    precomp<<<dim3(B_, 6), dim3(512), 0, stream>>>(x_mean, x_logs, S, MS, Cpart);
    gemm_nc<<<dim3(4, 16, 16), dim3(256), 0, stream>>>(z, S, MS, Cpart, NC);
    mas_forward<<<dim3(B_), dim3(64), 0, stream>>>(NC, dirs);
    mas_backtrack<<<dim3(B_), dim3(64), 0, stream>>>((const unsigned*)dirs, path);
    durations_ll<<<dim3(B_), dim3(512), 0, stream>>>(path, logw, out_l);
    gather_main<<<dim3(384, 16), dim3(256), 0, stream>>>(path, x_mean, x_logs, out_main);
    write_attn<<<dim3(B_ * TY_), dim3(128), 0, stream>>>(path, out_attn);
}

// Round 8
// 679.650 us; speedup vs baseline: 1.5563x; 1.0551x over previous
//
#include <hip/hip_runtime.h>
#include <hip/hip_bf16.h>
#include <math.h>

#define B_   16
#define D_   192
#define TX_  512
#define TY_  2048
#define NEGV (-1e9f)

// -------- workspace layout (bytes) --------
// S    : B*D*TX f32   @ 0          (6,291,456)
// MS   : B*D*TX f32   @ 6291456    (6,291,456)
// NC   : B*TY*TX f32  @ 12615680   (67,108,864)
// dirs : B*2048*64 u8 @ 79724544   (2,097,152)   [aliased: Cpart B*6*TX f32 in
//         first 196,608 B — consumed by gemm_nc BEFORE mas_forward writes dirs]
// path : B*TY  i32    @ 81821696   (131,072)

// -------- output layout (f32 elements) --------
// out_main [B,384,TY] @ 0, l_length [B] @ 12582912, attn [B,TY,TX] @ 12582928

typedef __attribute__((address_space(1))) const float glob_f;
typedef __attribute__((address_space(3))) float       lds_f;
typedef float f32x4 __attribute__((ext_vector_type(4)));   // real clang vector: valid asm "v" operand

// ============ Kernel A: precompute S, MS, partial C (deterministic) ============
__global__ __launch_bounds__(512) void precomp(const float* __restrict__ xm,
                                               const float* __restrict__ xl,
                                               float* __restrict__ S,
                                               float* __restrict__ MS,
                                               float* __restrict__ Cpart) {
    int b = blockIdx.x;
    int p = blockIdx.y;
    int x = threadIdx.x;
    size_t base = ((size_t)b * D_ + p * 32) * TX_;
    const float* mb = xm + base;
    const float* lb = xl + base;
    float* Sb  = S  + base;
    float* MSb = MS + base;
    float c = 0.f;
    for (int d = 0; d < 32; d++) {
        float lg = lb[d * TX_ + x];
        float mn = mb[d * TX_ + x];
        float s  = expf(-2.f * lg);
        float ms = mn * s;
        Sb[d * TX_ + x]  = s;
        MSb[d * TX_ + x] = ms;
        c += -0.9189385332046727f - lg - 0.5f * mn * mn * s;   // nc1 + nc4 terms
    }
    Cpart[(b * 6 + p) * TX_ + x] = c;
}

// ============ Kernel B: NC = A(z)*B(s,ms) + c, f32 128x128 tile, 8x8 micro ============
__global__ __launch_bounds__(256) void gemm_nc(const float* __restrict__ z,
                                               const float* __restrict__ S,
                                               const float* __restrict__ MS,
                                               const float* __restrict__ Cpart,
                                               float* __restrict__ NC) {
    int bx = blockIdx.x;            // 4  -> x tiles of 128
    int by = blockIdx.y;            // 16 -> y tiles of 128
    int b  = blockIdx.z;            // 16
    int tid = threadIdx.x;
    int tx = tid & 15, ty = tid >> 4;
    __shared__ __align__(16) float Zt[16 * 128];
    __shared__ __align__(16) float St[16 * 128];
    __shared__ __align__(16) float MSt[16 * 128];

    float acc[8][8];
#pragma unroll
    for (int i = 0; i < 8; i++)
#pragma unroll
        for (int j = 0; j < 8; j++) acc[i][j] = 0.f;

    int x0 = bx * 128, y0 = by * 128;
    const float* zb  = z  + (size_t)b * D_ * TY_;
    const float* Sb  = S  + (size_t)b * D_ * TX_;
    const float* MSb = MS + (size_t)b * D_ * TX_;

    for (int k0 = 0; k0 < D_; k0 += 16) {
        // stage 3 x (16 rows x 128 cols) via async global->LDS, 16B per lane
#pragma unroll
        for (int j = 0; j < 2; j++) {
            int f = tid + j * 256;          // 0..511 float4 slots
            int kk = f >> 5, c = (f & 31) * 4;
            __builtin_amdgcn_global_load_lds((glob_f*)(zb  + (size_t)(k0 + kk) * TY_ + y0 + c),
                                             (lds_f*)(Zt  + f * 4), 16, 0, 0);
            __builtin_amdgcn_global_load_lds((glob_f*)(Sb  + (size_t)(k0 + kk) * TX_ + x0 + c),
                                             (lds_f*)(St  + f * 4), 16, 0, 0);
            __builtin_amdgcn_global_load_lds((glob_f*)(MSb + (size_t)(k0 + kk) * TX_ + x0 + c),
                                             (lds_f*)(MSt + f * 4), 16, 0, 0);
        }
        __syncthreads();

#pragma unroll 2
        for (int kk = 0; kk < 16; kk++) {
            float4 z0 = *(const float4*)&Zt[kk * 128 + ty * 4];
            float4 z1 = *(const float4*)&Zt[kk * 128 + 64 + ty * 4];
            float4 s0 = *(const float4*)&St[kk * 128 + tx * 4];
            float4 s1 = *(const float4*)&St[kk * 128 + 64 + tx * 4];
            float4 m0 = *(const float4*)&MSt[kk * 128 + tx * 4];
            float4 m1 = *(const float4*)&MSt[kk * 128 + 64 + tx * 4];
            float4 u0, u1;
            u0.x = -0.5f * z0.x * z0.x; u0.y = -0.5f * z0.y * z0.y;
            u0.z = -0.5f * z0.z * z0.z; u0.w = -0.5f * z0.w * z0.w;
            u1.x = -0.5f * z1.x * z1.x; u1.y = -0.5f * z1.y * z1.y;
            u1.z = -0.5f * z1.z * z1.z; u1.w = -0.5f * z1.w * z1.w;
            float zz[8] = {z0.x, z0.y, z0.z, z0.w, z1.x, z1.y, z1.z, z1.w};
            float uu[8] = {u0.x, u0.y, u0.z, u0.w, u1.x, u1.y, u1.z, u1.w};
            float ss[8] = {s0.x, s0.y, s0.z, s0.w, s1.x, s1.y, s1.z, s1.w};
            float mm[8] = {m0.x, m0.y, m0.z, m0.w, m1.x, m1.y, m1.z, m1.w};
#pragma unroll
            for (int i = 0; i < 8; i++)
#pragma unroll
                for (int j = 0; j < 8; j++)
                    acc[i][j] += uu[i] * ss[j] + zz[i] * mm[j];
        }
        __syncthreads();
    }

    // column constants: sum 6 deterministic partials
    float cv[8] = {0, 0, 0, 0, 0, 0, 0, 0};
#pragma unroll
    for (int p = 0; p < 6; p++) {
        float4 c0 = *(const float4*)&Cpart[(b * 6 + p) * TX_ + x0 + tx * 4];
        float4 c1 = *(const float4*)&Cpart[(b * 6 + p) * TX_ + x0 + 64 + tx * 4];
        cv[0] += c0.x; cv[1] += c0.y; cv[2] += c0.z; cv[3] += c0.w;
        cv[4] += c1.x; cv[5] += c1.y; cv[6] += c1.z; cv[7] += c1.w;
    }

#pragma unroll
    for (int i = 0; i < 8; i++) {
        int y = y0 + ty * 4 + (i & 3) + 64 * (i >> 2);
        float4 o0, o1;
        o0.x = acc[i][0] + cv[0]; o0.y = acc[i][1] + cv[1];
        o0.z = acc[i][2] + cv[2]; o0.w = acc[i][3] + cv[3];
        o1.x = acc[i][4] + cv[4]; o1.y = acc[i][5] + cv[5];
        o1.z = acc[i][6] + cv[6]; o1.w = acc[i][7] + cv[7];
        *(float4*)&NC[((size_t)b * TY_ + y) * TX_ + x0 + tx * 4]      = o0;
        *(float4*)&NC[((size_t)b * TY_ + y) * TX_ + x0 + 64 + tx * 4] = o1;
    }
}

// ============ Kernel C: MAS forward DP — asm register ring + DPP boundary ============
// R12 = R7 (verified, 236.7us) + scheduling change only: the per-phase
// sched_barrier(0) after the tied vmcnt(45) is REMOVED. The "+v" ties pin
// every consumer of RA/RC below the wait, and volatile asm blocks stay
// ordered among themselves — so correctness is unchanged, but the compiler
// may now hoist the ~18 VALU ops that depend only on previous-row state
// (cmps, DPP, vd0) into the wait shadow. R7 accounting: 277 cy/row total,
// ~90-160 VALU issue, rest = bubbles + wait shadow; this targets the shadow.
__global__ __launch_bounds__(64, 1) void mas_forward(const float* __restrict__ NC,
                                                     unsigned char* __restrict__ dirs) {
    int b = blockIdx.x;
    int lane = threadIdx.x;
    const float* ncb = NC + (size_t)b * TY_ * TX_;
    int voff = lane * 32;                      // byte offset of this lane's 8 floats

    // nc[0,0]: compiler-tracked load; its waitcnt lands before the asm ring loads
    float nc00 = ncb[0];
    asm volatile("" :: "v"(nc00));

    float v[8];
#pragma unroll
    for (int j = 0; j < 8; j++) v[j] = NEGV;
    if (lane == 0) v[0] = nc00;

    float bound = NEGV;   // lane-1's v[7] after previous row (via DPP)
    int negi = __float_as_int(NEGV);

    auto row_step = [&](f32x4 a, f32x4 c, int y, bool mask) -> unsigned {
        float ncv[8] = {a.x, a.y, a.z, a.w, c.x, c.y, c.z, c.w};
        float vd0 = (lane == 0) ? NEGV : bound;
        // element 7 first: compute, mask, and launch the cross-lane transfer
        float v6o = v[6], v7o = v[7];
        float v7n = ncv[7] + fmaxf(v7o, v6o);
        if (mask && y < 511 && lane * 8 + 7 > y) v7n = NEGV;
        // DPP wf_sr1: lane l <- lane l-1's v7n. Pure VALU.
        bound = __int_as_float(__builtin_amdgcn_update_dpp(
            negi, __float_as_int(v7n), 0x138, 0xf, 0xf, false));
        unsigned bits = (v6o > v7o) ? 0x80u : 0u;
        float vd = vd0;
#pragma unroll
        for (int j = 0; j < 7; j++) {
            float vp = v[j];
            bits |= (vd > vp) ? (1u << j) : 0u;
            v[j] = ncv[j] + fmaxf(vp, vd);
            vd = vp;
        }
        if (mask && y < 511) {
            int xb = lane * 8;
#pragma unroll
            for (int j = 0; j < 7; j++)
                if (xb + j > y) v[j] = NEGV;
        }
        v[7] = v7n;
        return bits;
    };

    f32x4 r0a, r0c, r1a, r1c, r2a, r2c, r3a, r3c, r4a, r4c, r5a, r5c, r6a, r6c, r7a, r7c;
    f32x4 r8a, r8c, r9a, r9c, r10a, r10c, r11a, r11c, r12a, r12c, r13a, r13c, r14a, r14c, r15a, r15c;

    const float* pf = ncb + TX_;                         // next row to load
    unsigned char* dp = dirs + (size_t)b * 2048 * 64;    // dirs row 0 base

#define LOADPAIR(RA, RC)                                                   \
    do {                                                                   \
        asm volatile("global_load_dwordx4 %0, %2, %1 offset:0"             \
                     : "=v"(RA) : "s"(pf), "v"(voff));                     \
        asm volatile("global_load_dwordx4 %0, %2, %1 offset:16"            \
                     : "=v"(RC) : "s"(pf), "v"(voff));                     \
        pf += TX_;                                                         \
    } while (0)

#define STOREBITS(BITS)                                                    \
    asm volatile("global_store_byte %1, %2, %0" :: "s"(dp), "v"(lane), "v"(BITS))

#define PHASE(RA, RC, MASKED)                                              \
    do {                                                                   \
        asm volatile("s_waitcnt vmcnt(45)" : "+v"(RA), "+v"(RC));          \
        unsigned bits_ = row_step(RA, RC, y, MASKED);                      \
        STOREBITS(bits_);                                                  \
        LOADPAIR(RA, RC);                                                  \
        dp += 64;                                                          \
        y++;                                                               \
    } while (0)

#define PH16(MASKED)                                                       \
    PHASE(r0a, r0c, MASKED);  PHASE(r1a, r1c, MASKED);                     \
    PHASE(r2a, r2c, MASKED);  PHASE(r3a, r3c, MASKED);                     \
    PHASE(r4a, r4c, MASKED);  PHASE(r5a, r5c, MASKED);                     \
    PHASE(r6a, r6c, MASKED);  PHASE(r7a, r7c, MASKED);                     \
    PHASE(r8a, r8c, MASKED);  PHASE(r9a, r9c, MASKED);                     \
    PHASE(r10a, r10c, MASKED); PHASE(r11a, r11c, MASKED);                  \
    PHASE(r12a, r12c, MASKED); PHASE(r13a, r13c, MASKED);                  \
    PHASE(r14a, r14c, MASKED); PHASE(r15a, r15c, MASKED);

    // prologue: rows 1..16 into ring slots 0..15, then drain once
    LOADPAIR(r0a, r0c);   LOADPAIR(r1a, r1c);   LOADPAIR(r2a, r2c);   LOADPAIR(r3a, r3c);
    LOADPAIR(r4a, r4c);   LOADPAIR(r5a, r5c);   LOADPAIR(r6a, r6c);   LOADPAIR(r7a, r7c);
    LOADPAIR(r8a, r8c);   LOADPAIR(r9a, r9c);   LOADPAIR(r10a, r10c); LOADPAIR(r11a, r11c);
    LOADPAIR(r12a, r12c); LOADPAIR(r13a, r13c); LOADPAIR(r14a, r14c); LOADPAIR(r15a, r15c);
    asm volatile("s_waitcnt vmcnt(0)" ::: "memory");
    __builtin_amdgcn_sched_barrier(0);

    int y = 1;
    // masked phase: rows 1..512 (mask condition y<511 applied inside)
    for (int t = 0; t < 32; t++) {
        PH16(true)
    }
    // unmasked phase: rows 513..2016
    for (int t = 32; t < 126; t++) {
        PH16(false)
    }
    // rows 2017..2031 with prefetch (loads rows 2033..2047)
    PHASE(r0a, r0c, false);  PHASE(r1a, r1c, false);
    PHASE(r2a, r2c, false);  PHASE(r3a, r3c, false);
    PHASE(r4a, r4c, false);  PHASE(r5a, r5c, false);
    PHASE(r6a, r6c, false);  PHASE(r7a, r7c, false);
    PHASE(r8a, r8c, false);  PHASE(r9a, r9c, false);
    PHASE(r10a, r10c, false); PHASE(r11a, r11c, false);
    PHASE(r12a, r12c, false); PHASE(r13a, r13c, false);
    PHASE(r14a, r14c, false);
    // row 2032: wait(45) exactly releases its loads; no further prefetch
    {
        asm volatile("s_waitcnt vmcnt(45)" : "+v"(r15a), "+v"(r15c));
        unsigned bits_ = row_step(r15a, r15c, y, false);
        STOREBITS(bits_);
        dp += 64;
        y++;
    }

    // epilogue: rows 2033..2047 from ring slots 0..14. vmcnt(1): newest op is
    // the row-2032 store; all ring loads (older) are complete after this.
    asm volatile("s_waitcnt vmcnt(1)"
                 : "+v"(r0a), "+v"(r0c), "+v"(r1a), "+v"(r1c),
                   "+v"(r2a), "+v"(r2c), "+v"(r3a), "+v"(r3c),
                   "+v"(r4a), "+v"(r4c), "+v"(r5a), "+v"(r5c),
                   "+v"(r6a), "+v"(r6c), "+v"(r7a), "+v"(r7c));
    asm volatile("s_waitcnt vmcnt(1)"
                 : "+v"(r8a), "+v"(r8c), "+v"(r9a), "+v"(r9c),
                   "+v"(r10a), "+v"(r10c), "+v"(r11a), "+v"(r11c),
                   "+v"(r12a), "+v"(r12c), "+v"(r13a), "+v"(r13c),
                   "+v"(r14a), "+v"(r14c));
    __builtin_amdgcn_sched_barrier(0);
    {
        unsigned bb;
        bb = row_step(r0a, r0c, y, false);  STOREBITS(bb); dp += 64; y++;
        bb = row_step(r1a, r1c, y, false);  STOREBITS(bb); dp += 64; y++;
        bb = row_step(r2a, r2c, y, false);  STOREBITS(bb); dp += 64; y++;
        bb = row_step(r3a, r3c, y, false);  STOREBITS(bb); dp += 64; y++;
        bb = row_step(r4a, r4c, y, false);  STOREBITS(bb); dp += 64; y++;
        bb = row_step(r5a, r5c, y, false);  STOREBITS(bb); dp += 64; y++;
        bb = row_step(r6a, r6c, y, false);  STOREBITS(bb); dp += 64; y++;
        bb = row_step(r7a, r7c, y, false);  STOREBITS(bb); dp += 64; y++;
        bb = row_step(r8a, r8c, y, false);  STOREBITS(bb); dp += 64; y++;
        bb = row_step(r9a, r9c, y, false);  STOREBITS(bb); dp += 64; y++;
        bb = row_step(r10a, r10c, y, false); STOREBITS(bb); dp += 64; y++;
        bb = row_step(r11a, r11c, y, false); STOREBITS(bb); dp += 64; y++;
        bb = row_step(r12a, r12c, y, false); STOREBITS(bb); dp += 64; y++;
        bb = row_step(r13a, r13c, y, false); STOREBITS(bb); dp += 64; y++;
        bb = row_step(r14a, r14c, y, false); STOREBITS(bb);
    }

#undef PH16
#undef PHASE
#undef STOREBITS
#undef LOADPAIR
}

// ============ Kernel D: backtrack — readlane/scalar rewrite ============
// R12: the t-loop broadcast used 3 x __shfl per step = 3 DS-pipe round trips
// x 2047 serial steps (est. 60-90us total). t is UNIFORM (loop counter), so
// readlane is legal and the broadcast becomes 3 VALU ops with SGPR results;
// idx/off/w become uniform -> the whole update chain scalarizes (SALU).
// Same algorithm, same window invariants (idx decreases by <=1 per row, so
// the 96-col window holds for 64 steps; off in [0,95] -- unchanged from the
// verified shfl version).
__global__ __launch_bounds__(64, 1) void mas_backtrack(const unsigned* __restrict__ dirs,
                                                       int* __restrict__ path) {
    int b = blockIdx.x;
    int lane = threadIdx.x;
    const unsigned* db = dirs + (size_t)b * 2048 * 16;   // 16 dwords per row
    int idx = TX_ - 1;                                   // path[2047]

    for (int y_hi = 2047; y_hi >= 1; y_hi -= 64) {
        int wb = (idx >> 5) - 2;
        if (wb < 0) wb = 0;
        if (wb > 13) wb = 13;                            // clamp: garbage-proof
        int base = wb << 5;
        int y = y_hi - lane;
        unsigned w0 = 0, w1 = 0, w2 = 0;
        if (y >= 1) {
            const unsigned* r = db + (size_t)(y - 1) * 16 + wb;
            w0 = r[0]; w1 = r[1]; w2 = r[2];
        }
        int steps = (y_hi < 64) ? y_hi : 64;
        int my_path = 0;
#pragma unroll
        for (int t = 0; t < 64; t++) {
            if (t < steps) {
                unsigned u0 = (unsigned)__builtin_amdgcn_readlane((int)w0, t);
                unsigned u1 = (unsigned)__builtin_amdgcn_readlane((int)w1, t);
                unsigned u2 = (unsigned)__builtin_amdgcn_readlane((int)w2, t);
                if (lane == t) my_path = idx;
                int off = idx - base;
                unsigned w = (off < 32) ? u0 : ((off < 64) ? u1 : u2);
                idx -= (int)((w >> (off & 31)) & 1u);
            }
        }
        if (lane < steps) path[b * TY_ + (y_hi - lane)] = my_path;
    }
    if (lane == 0) path[b * TY_ + 0] = idx;
}

// ============ Kernel E: durations + l_length ============
__global__ __launch_bounds__(512) void durations_ll(const int* __restrict__ path,
                                                    const float* __restrict__ logw,
                                                    float* __restrict__ out_l) {
    int b = blockIdx.x;
    int tid = threadIdx.x;
    __shared__ int wcnt[TX_];
    __shared__ float partial[8];
    wcnt[tid] = 0;
    __syncthreads();
    for (int y = tid; y < TY_; y += 512) {
        int p = path[b * TY_ + y];
        if ((unsigned)p > 511u) p = 0;                   // clamp: garbage-proof
        atomicAdd(&wcnt[p], 1);
    }
    __syncthreads();
    float t = logw[b * TX_ + tid] - logf((float)wcnt[tid] + 1e-6f);
    float sq = t * t;
#pragma unroll
    for (int off = 32; off > 0; off >>= 1) sq += __shfl_down(sq, off);
    if ((tid & 63) == 0) partial[tid >> 6] = sq;
    __syncthreads();
    if (tid == 0) {
        float s = 0.f;
#pragma unroll
        for (int i = 0; i < 8; i++) s += partial[i];
        out_l[b] = s;
    }
}

// ============ Kernel F: gather out_main ============
__global__ __launch_bounds__(256) void gather_main(const int* __restrict__ path,
                                                   const float* __restrict__ xm,
                                                   const float* __restrict__ xl,
                                                   float* __restrict__ out) {
    int c = blockIdx.x;      // 0..383
    int b = blockIdx.y;      // 0..15
    int tid = threadIdx.x;
    const float* src = (c < D_) ? (xm + ((size_t)b * D_ + c) * TX_)
                                : (xl + ((size_t)b * D_ + (c - D_)) * TX_);
    const int* pb = path + b * TY_;
    float* ob = out + ((size_t)b * 2 * D_ + c) * TY_;
#pragma unroll
    for (int k = 0; k < 8; k++) {
        int y = tid + k * 256;
        int p = pb[y];
        if ((unsigned)p > 511u) p = 0;                   // clamp: garbage-proof
        ob[y] = src[p];
    }
}

// ============ Kernel G: write one-hot attn ============
__global__ __launch_bounds__(128) void write_attn(const int* __restrict__ path,
                                                  float* __restrict__ attn) {
    int blk = blockIdx.x;            // b*2048 + y
    int b = blk >> 11;
    int y = blk & 2047;
    int tid = threadIdx.x;           // covers x in [4*tid, 4*tid+4)
    int p = path[b * TY_ + y];
    float4 val = make_float4(0.f, 0.f, 0.f, 0.f);
    if ((p >> 2) == tid) {
        int r = p & 3;
        if (r == 0) val.x = 1.f;
        else if (r == 1) val.y = 1.f;
        else if (r == 2) val.z = 1.f;
        else val.w = 1.f;
    }
    ((float4*)attn)[((size_t)blk) * 128 + tid] = val;
}

extern "C" void kernel_launch(void* const* d_in, const int* in_sizes, int n_in,
                              void* d_out, int out_size, void* d_ws, size_t ws_size,
                              hipStream_t stream) {
    const float* x_mean = (const float*)d_in[0];
    const float* x_logs = (const float*)d_in[1];
    const float* z      = (const float*)d_in[2];
    const float* logw   = (const float*)d_in[3];
    float* out = (float*)d_out;

    char* ws = (char*)d_ws;
    float* S            = (float*)(ws + 0);
    float* MS           = (float*)(ws + 6291456);
    float* NC           = (float*)(ws + 12615680);
    unsigned char* dirs = (unsigned char*)(ws + 79724544);
    float* Cpart        = (float*)(ws + 79724544);   // aliases dirs; dead before mas_forward
    int* path           = (int*)(ws + 81821696);

    float* out_main = out;                 // [B,384,TY]
    float* out_l    = out + 12582912;      // [B]
    float* out_attn = out + 12582928;      // [B,TY,TX]

    precomp<<<dim3(B_, 6), dim3(512), 0, stream>>>(x_mean, x_logs, S, MS, Cpart);
    gemm_nc<<<dim3(4, 16, 16), dim3(256), 0, stream>>>(z, S, MS, Cpart, NC);
    mas_forward<<<dim3(B_), dim3(64), 0, stream>>>(NC, dirs);
    mas_backtrack<<<dim3(B_), dim3(64), 0, stream>>>((const unsigned*)dirs, path);
    durations_ll<<<dim3(B_), dim3(512), 0, stream>>>(path, logw, out_l);
    gather_main<<<dim3(384, 16), dim3(256), 0, stream>>>(path, x_mean, x_logs, out_main);
    write_attn<<<dim3(B_ * TY_), dim3(128), 0, stream>>>(path, out_attn);
}

// Round 11
// 678.075 us; speedup vs baseline: 1.5599x; 1.0023x over previous
//
#include <hip/hip_runtime.h>
#include <hip/hip_bf16.h>
#include <math.h>

#define B_   16
#define D_   192
#define TX_  512
#define TY_  2048
#define NEGV (-1e9f)

// -------- workspace layout (bytes) --------
// S    : B*D*TX f32   @ 0          (6,291,456)
// MS   : B*D*TX f32   @ 6291456    (6,291,456)
// NC   : B*TY*TX f32  @ 12615680   (67,108,864)
// dirs : B*2048*64 u8 @ 79724544   (2,097,152)   [aliased: Cpart B*6*TX f32 in
//         first 196,608 B — consumed by gemm_nc BEFORE mas_forward writes dirs]
// path : B*TY  i32    @ 81821696   (131,072)

// -------- output layout (f32 elements) --------
// out_main [B,384,TY] @ 0, l_length [B] @ 12582912, attn [B,TY,TX] @ 12582928

typedef __attribute__((address_space(1))) const float glob_f;
typedef __attribute__((address_space(3))) float       lds_f;
typedef float f32x4 __attribute__((ext_vector_type(4)));   // real clang vector: valid asm "v" operand

// ============ Kernel A: precompute S, MS, partial C (deterministic) ============
__global__ __launch_bounds__(512) void precomp(const float* __restrict__ xm,
                                               const float* __restrict__ xl,
                                               float* __restrict__ S,
                                               float* __restrict__ MS,
                                               float* __restrict__ Cpart) {
    int b = blockIdx.x;
    int p = blockIdx.y;
    int x = threadIdx.x;
    size_t base = ((size_t)b * D_ + p * 32) * TX_;
    const float* mb = xm + base;
    const float* lb = xl + base;
    float* Sb  = S  + base;
    float* MSb = MS + base;
    float c = 0.f;
    for (int d = 0; d < 32; d++) {
        float lg = lb[d * TX_ + x];
        float mn = mb[d * TX_ + x];
        float s  = expf(-2.f * lg);
        float ms = mn * s;
        Sb[d * TX_ + x]  = s;
        MSb[d * TX_ + x] = ms;
        c += -0.9189385332046727f - lg - 0.5f * mn * mn * s;   // nc1 + nc4 terms
    }
    Cpart[(b * 6 + p) * TX_ + x] = c;
}

// ============ Kernel B: NC = A(z)*B(s,ms) + c, f32 128x128 tile, 8x8 micro ============
__global__ __launch_bounds__(256) void gemm_nc(const float* __restrict__ z,
                                               const float* __restrict__ S,
                                               const float* __restrict__ MS,
                                               const float* __restrict__ Cpart,
                                               float* __restrict__ NC) {
    int bx = blockIdx.x;            // 4  -> x tiles of 128
    int by = blockIdx.y;            // 16 -> y tiles of 128
    int b  = blockIdx.z;            // 16
    int tid = threadIdx.x;
    int tx = tid & 15, ty = tid >> 4;
    __shared__ __align__(16) float Zt[16 * 128];
    __shared__ __align__(16) float St[16 * 128];
    __shared__ __align__(16) float MSt[16 * 128];

    float acc[8][8];
#pragma unroll
    for (int i = 0; i < 8; i++)
#pragma unroll
        for (int j = 0; j < 8; j++) acc[i][j] = 0.f;

    int x0 = bx * 128, y0 = by * 128;
    const float* zb  = z  + (size_t)b * D_ * TY_;
    const float* Sb  = S  + (size_t)b * D_ * TX_;
    const float* MSb = MS + (size_t)b * D_ * TX_;

    for (int k0 = 0; k0 < D_; k0 += 16) {
        // stage 3 x (16 rows x 128 cols) via async global->LDS, 16B per lane
#pragma unroll
        for (int j = 0; j < 2; j++) {
            int f = tid + j * 256;          // 0..511 float4 slots
            int kk = f >> 5, c = (f & 31) * 4;
            __builtin_amdgcn_global_load_lds((glob_f*)(zb  + (size_t)(k0 + kk) * TY_ + y0 + c),
                                             (lds_f*)(Zt  + f * 4), 16, 0, 0);
            __builtin_amdgcn_global_load_lds((glob_f*)(Sb  + (size_t)(k0 + kk) * TX_ + x0 + c),
                                             (lds_f*)(St  + f * 4), 16, 0, 0);
            __builtin_amdgcn_global_load_lds((glob_f*)(MSb + (size_t)(k0 + kk) * TX_ + x0 + c),
                                             (lds_f*)(MSt + f * 4), 16, 0, 0);
        }
        __syncthreads();

#pragma unroll 2
        for (int kk = 0; kk < 16; kk++) {
            float4 z0 = *(const float4*)&Zt[kk * 128 + ty * 4];
            float4 z1 = *(const float4*)&Zt[kk * 128 + 64 + ty * 4];
            float4 s0 = *(const float4*)&St[kk * 128 + tx * 4];
            float4 s1 = *(const float4*)&St[kk * 128 + 64 + tx * 4];
            float4 m0 = *(const float4*)&MSt[kk * 128 + tx * 4];
            float4 m1 = *(const float4*)&MSt[kk * 128 + 64 + tx * 4];
            float4 u0, u1;
            u0.x = -0.5f * z0.x * z0.x; u0.y = -0.5f * z0.y * z0.y;
            u0.z = -0.5f * z0.z * z0.z; u0.w = -0.5f * z0.w * z0.w;
            u1.x = -0.5f * z1.x * z1.x; u1.y = -0.5f * z1.y * z1.y;
            u1.z = -0.5f * z1.z * z1.z; u1.w = -0.5f * z1.w * z1.w;
            float zz[8] = {z0.x, z0.y, z0.z, z0.w, z1.x, z1.y, z1.z, z1.w};
            float uu[8] = {u0.x, u0.y, u0.z, u0.w, u1.x, u1.y, u1.z, u1.w};
            float ss[8] = {s0.x, s0.y, s0.z, s0.w, s1.x, s1.y, s1.z, s1.w};
            float mm[8] = {m0.x, m0.y, m0.z, m0.w, m1.x, m1.y, m1.z, m1.w};
#pragma unroll
            for (int i = 0; i < 8; i++)
#pragma unroll
                for (int j = 0; j < 8; j++)
                    acc[i][j] += uu[i] * ss[j] + zz[i] * mm[j];
        }
        __syncthreads();
    }

    // column constants: sum 6 deterministic partials
    float cv[8] = {0, 0, 0, 0, 0, 0, 0, 0};
#pragma unroll
    for (int p = 0; p < 6; p++) {
        float4 c0 = *(const float4*)&Cpart[(b * 6 + p) * TX_ + x0 + tx * 4];
        float4 c1 = *(const float4*)&Cpart[(b * 6 + p) * TX_ + x0 + 64 + tx * 4];
        cv[0] += c0.x; cv[1] += c0.y; cv[2] += c0.z; cv[3] += c0.w;
        cv[4] += c1.x; cv[5] += c1.y; cv[6] += c1.z; cv[7] += c1.w;
    }

#pragma unroll
    for (int i = 0; i < 8; i++) {
        int y = y0 + ty * 4 + (i & 3) + 64 * (i >> 2);
        float4 o0, o1;
        o0.x = acc[i][0] + cv[0]; o0.y = acc[i][1] + cv[1];
        o0.z = acc[i][2] + cv[2]; o0.w = acc[i][3] + cv[3];
        o1.x = acc[i][4] + cv[4]; o1.y = acc[i][5] + cv[5];
        o1.z = acc[i][6] + cv[6]; o1.w = acc[i][7] + cv[7];
        *(float4*)&NC[((size_t)b * TY_ + y) * TX_ + x0 + tx * 4]      = o0;
        *(float4*)&NC[((size_t)b * TY_ + y) * TX_ + x0 + 64 + tx * 4] = o1;
    }
}

// ============ Kernel C: MAS forward DP — asm register ring + DPP boundary ============
// R15 = lock-in of the best VERIFIED configuration. This is R7's mas_forward
// exactly (236.7us, absmax 0): asm register ring, counted vmcnt(45), DPP
// wf_sr1 boundary with explicit lane-0 select, AND sched_barrier(0) after
// each tied wait — R12 measured that removing it costs +6.3us. The 2-wave
// column-split arc (R8-R10, R13-R14) is permanently abandoned: 6 rounds,
// zero passing runs, shifting failure signatures.
// All vmcnt-counted ops are volatile inline asm in pinned program order —
// per row exactly {global_store_byte dirs(y), loadA(y+16), loadC(y+16)}.
// Loads for row y issue 16 phases early => at phase y's wait the newer-op
// count is 15*3=45 => s_waitcnt vmcnt(45) releases row y and keeps 15 rows
// in flight. The wait TIES the consumed ring registers ("+v").
__global__ __launch_bounds__(64, 1) void mas_forward(const float* __restrict__ NC,
                                                     unsigned char* __restrict__ dirs) {
    int b = blockIdx.x;
    int lane = threadIdx.x;
    const float* ncb = NC + (size_t)b * TY_ * TX_;
    int voff = lane * 32;                      // byte offset of this lane's 8 floats

    // nc[0,0]: compiler-tracked load; its waitcnt lands before the asm ring loads
    float nc00 = ncb[0];
    asm volatile("" :: "v"(nc00));

    float v[8];
#pragma unroll
    for (int j = 0; j < 8; j++) v[j] = NEGV;
    if (lane == 0) v[0] = nc00;

    float bound = NEGV;   // lane-1's v[7] after previous row (via DPP)
    int negi = __float_as_int(NEGV);

    auto row_step = [&](f32x4 a, f32x4 c, int y, bool mask) -> unsigned {
        float ncv[8] = {a.x, a.y, a.z, a.w, c.x, c.y, c.z, c.w};
        float vd0 = (lane == 0) ? NEGV : bound;
        // element 7 first: compute, mask, and launch the cross-lane transfer
        float v6o = v[6], v7o = v[7];
        float v7n = ncv[7] + fmaxf(v7o, v6o);
        if (mask && y < 511 && lane * 8 + 7 > y) v7n = NEGV;
        // DPP wf_sr1: lane l <- lane l-1's v7n. Pure VALU.
        bound = __int_as_float(__builtin_amdgcn_update_dpp(
            negi, __float_as_int(v7n), 0x138, 0xf, 0xf, false));
        unsigned bits = (v6o > v7o) ? 0x80u : 0u;
        float vd = vd0;
#pragma unroll
        for (int j = 0; j < 7; j++) {
            float vp = v[j];
            bits |= (vd > vp) ? (1u << j) : 0u;
            v[j] = ncv[j] + fmaxf(vp, vd);
            vd = vp;
        }
        if (mask && y < 511) {
            int xb = lane * 8;
#pragma unroll
            for (int j = 0; j < 7; j++)
                if (xb + j > y) v[j] = NEGV;
        }
        v[7] = v7n;
        return bits;
    };

    f32x4 r0a, r0c, r1a, r1c, r2a, r2c, r3a, r3c, r4a, r4c, r5a, r5c, r6a, r6c, r7a, r7c;
    f32x4 r8a, r8c, r9a, r9c, r10a, r10c, r11a, r11c, r12a, r12c, r13a, r13c, r14a, r14c, r15a, r15c;

    const float* pf = ncb + TX_;                         // next row to load
    unsigned char* dp = dirs + (size_t)b * 2048 * 64;    // dirs row 0 base

#define LOADPAIR(RA, RC)                                                   \
    do {                                                                   \
        asm volatile("global_load_dwordx4 %0, %2, %1 offset:0"             \
                     : "=v"(RA) : "s"(pf), "v"(voff));                     \
        asm volatile("global_load_dwordx4 %0, %2, %1 offset:16"            \
                     : "=v"(RC) : "s"(pf), "v"(voff));                     \
        pf += TX_;                                                         \
    } while (0)

#define STOREBITS(BITS)                                                    \
    asm volatile("global_store_byte %1, %2, %0" :: "s"(dp), "v"(lane), "v"(BITS))

#define PHASE(RA, RC, MASKED)                                              \
    do {                                                                   \
        asm volatile("s_waitcnt vmcnt(45)" : "+v"(RA), "+v"(RC));          \
        __builtin_amdgcn_sched_barrier(0);                                 \
        unsigned bits_ = row_step(RA, RC, y, MASKED);                      \
        STOREBITS(bits_);                                                  \
        LOADPAIR(RA, RC);                                                  \
        dp += 64;                                                          \
        y++;                                                               \
    } while (0)

#define PH16(MASKED)                                                       \
    PHASE(r0a, r0c, MASKED);  PHASE(r1a, r1c, MASKED);                     \
    PHASE(r2a, r2c, MASKED);  PHASE(r3a, r3c, MASKED);                     \
    PHASE(r4a, r4c, MASKED);  PHASE(r5a, r5c, MASKED);                     \
    PHASE(r6a, r6c, MASKED);  PHASE(r7a, r7c, MASKED);                     \
    PHASE(r8a, r8c, MASKED);  PHASE(r9a, r9c, MASKED);                     \
    PHASE(r10a, r10c, MASKED); PHASE(r11a, r11c, MASKED);                  \
    PHASE(r12a, r12c, MASKED); PHASE(r13a, r13c, MASKED);                  \
    PHASE(r14a, r14c, MASKED); PHASE(r15a, r15c, MASKED);

    // prologue: rows 1..16 into ring slots 0..15, then drain once
    LOADPAIR(r0a, r0c);   LOADPAIR(r1a, r1c);   LOADPAIR(r2a, r2c);   LOADPAIR(r3a, r3c);
    LOADPAIR(r4a, r4c);   LOADPAIR(r5a, r5c);   LOADPAIR(r6a, r6c);   LOADPAIR(r7a, r7c);
    LOADPAIR(r8a, r8c);   LOADPAIR(r9a, r9c);   LOADPAIR(r10a, r10c); LOADPAIR(r11a, r11c);
    LOADPAIR(r12a, r12c); LOADPAIR(r13a, r13c); LOADPAIR(r14a, r14c); LOADPAIR(r15a, r15c);
    asm volatile("s_waitcnt vmcnt(0)" ::: "memory");
    __builtin_amdgcn_sched_barrier(0);

    int y = 1;
    // masked phase: rows 1..512 (mask condition y<511 applied inside)
    for (int t = 0; t < 32; t++) {
        PH16(true)
    }
    // unmasked phase: rows 513..2016
    for (int t = 32; t < 126; t++) {
        PH16(false)
    }
    // rows 2017..2031 with prefetch (loads rows 2033..2047)
    PHASE(r0a, r0c, false);  PHASE(r1a, r1c, false);
    PHASE(r2a, r2c, false);  PHASE(r3a, r3c, false);
    PHASE(r4a, r4c, false);  PHASE(r5a, r5c, false);
    PHASE(r6a, r6c, false);  PHASE(r7a, r7c, false);
    PHASE(r8a, r8c, false);  PHASE(r9a, r9c, false);
    PHASE(r10a, r10c, false); PHASE(r11a, r11c, false);
    PHASE(r12a, r12c, false); PHASE(r13a, r13c, false);
    PHASE(r14a, r14c, false);
    // row 2032: wait(45) exactly releases its loads; no further prefetch
    {
        asm volatile("s_waitcnt vmcnt(45)" : "+v"(r15a), "+v"(r15c));
        __builtin_amdgcn_sched_barrier(0);
        unsigned bits_ = row_step(r15a, r15c, y, false);
        STOREBITS(bits_);
        dp += 64;
        y++;
    }

    // epilogue: rows 2033..2047 from ring slots 0..14. vmcnt(1): newest op is
    // the row-2032 store; all ring loads (older) are complete after this.
    asm volatile("s_waitcnt vmcnt(1)"
                 : "+v"(r0a), "+v"(r0c), "+v"(r1a), "+v"(r1c),
                   "+v"(r2a), "+v"(r2c), "+v"(r3a), "+v"(r3c),
                   "+v"(r4a), "+v"(r4c), "+v"(r5a), "+v"(r5c),
                   "+v"(r6a), "+v"(r6c), "+v"(r7a), "+v"(r7c));
    asm volatile("s_waitcnt vmcnt(1)"
                 : "+v"(r8a), "+v"(r8c), "+v"(r9a), "+v"(r9c),
                   "+v"(r10a), "+v"(r10c), "+v"(r11a), "+v"(r11c),
                   "+v"(r12a), "+v"(r12c), "+v"(r13a), "+v"(r13c),
                   "+v"(r14a), "+v"(r14c));
    __builtin_amdgcn_sched_barrier(0);
    {
        unsigned bb;
        bb = row_step(r0a, r0c, y, false);  STOREBITS(bb); dp += 64; y++;
        bb = row_step(r1a, r1c, y, false);  STOREBITS(bb); dp += 64; y++;
        bb = row_step(r2a, r2c, y, false);  STOREBITS(bb); dp += 64; y++;
        bb = row_step(r3a, r3c, y, false);  STOREBITS(bb); dp += 64; y++;
        bb = row_step(r4a, r4c, y, false);  STOREBITS(bb); dp += 64; y++;
        bb = row_step(r5a, r5c, y, false);  STOREBITS(bb); dp += 64; y++;
        bb = row_step(r6a, r6c, y, false);  STOREBITS(bb); dp += 64; y++;
        bb = row_step(r7a, r7c, y, false);  STOREBITS(bb); dp += 64; y++;
        bb = row_step(r8a, r8c, y, false);  STOREBITS(bb); dp += 64; y++;
        bb = row_step(r9a, r9c, y, false);  STOREBITS(bb); dp += 64; y++;
        bb = row_step(r10a, r10c, y, false); STOREBITS(bb); dp += 64; y++;
        bb = row_step(r11a, r11c, y, false); STOREBITS(bb); dp += 64; y++;
        bb = row_step(r12a, r12c, y, false); STOREBITS(bb); dp += 64; y++;
        bb = row_step(r13a, r13c, y, false); STOREBITS(bb); dp += 64; y++;
        bb = row_step(r14a, r14c, y, false); STOREBITS(bb);
    }

#undef PH16
#undef PHASE
#undef STOREBITS
#undef LOADPAIR
}

// ============ Kernel D: backtrack — readlane/scalar (verified R12) ============
// t is uniform -> readlane replaces the 3 DS-pipe shfl round trips per step
// with 3 VALU ops; the idx chain scalarizes. Byte-dirs layout (64B/row).
__global__ __launch_bounds__(64, 1) void mas_backtrack(const unsigned* __restrict__ dirs,
                                                       int* __restrict__ path) {
    int b = blockIdx.x;
    int lane = threadIdx.x;
    const unsigned* db = dirs + (size_t)b * 2048 * 16;   // 16 dwords per row
    int idx = TX_ - 1;                                   // path[2047]

    for (int y_hi = 2047; y_hi >= 1; y_hi -= 64) {
        int wb = (idx >> 5) - 2;
        if (wb < 0) wb = 0;
        if (wb > 13) wb = 13;                            // clamp: garbage-proof
        int base = wb << 5;
        int y = y_hi - lane;
        unsigned w0 = 0, w1 = 0, w2 = 0;
        if (y >= 1) {
            const unsigned* r = db + (size_t)(y - 1) * 16 + wb;
            w0 = r[0]; w1 = r[1]; w2 = r[2];
        }
        int steps = (y_hi < 64) ? y_hi : 64;
        int my_path = 0;
#pragma unroll
        for (int t = 0; t < 64; t++) {
            if (t < steps) {
                unsigned u0 = (unsigned)__builtin_amdgcn_readlane((int)w0, t);
                unsigned u1 = (unsigned)__builtin_amdgcn_readlane((int)w1, t);
                unsigned u2 = (unsigned)__builtin_amdgcn_readlane((int)w2, t);
                if (lane == t) my_path = idx;
                int off = idx - base;
                unsigned w = (off < 32) ? u0 : ((off < 64) ? u1 : u2);
                idx -= (int)((w >> (off & 31)) & 1u);
            }
        }
        if (lane < steps) path[b * TY_ + (y_hi - lane)] = my_path;
    }
    if (lane == 0) path[b * TY_ + 0] = idx;
}

// ============ Kernel E: durations + l_length ============
__global__ __launch_bounds__(512) void durations_ll(const int* __restrict__ path,
                                                    const float* __restrict__ logw,
                                                    float* __restrict__ out_l) {
    int b = blockIdx.x;
    int tid = threadIdx.x;
    __shared__ int wcnt[TX_];
    __shared__ float partial[8];
    wcnt[tid] = 0;
    __syncthreads();
    for (int y = tid; y < TY_; y += 512) {
        int p = path[b * TY_ + y];
        if ((unsigned)p > 511u) p = 0;                   // clamp: garbage-proof
        atomicAdd(&wcnt[p], 1);
    }
    __syncthreads();
    float t = logw[b * TX_ + tid] - logf((float)wcnt[tid] + 1e-6f);
    float sq = t * t;
#pragma unroll
    for (int off = 32; off > 0; off >>= 1) sq += __shfl_down(sq, off);
    if ((tid & 63) == 0) partial[tid >> 6] = sq;
    __syncthreads();
    if (tid == 0) {
        float s = 0.f;
#pragma unroll
        for (int i = 0; i < 8; i++) s += partial[i];
        out_l[b] = s;
    }
}

// ============ Kernel F: gather out_main ============
__global__ __launch_bounds__(256) void gather_main(const int* __restrict__ path,
                                                   const float* __restrict__ xm,
                                                   const float* __restrict__ xl,
                                                   float* __restrict__ out) {
    int c = blockIdx.x;      // 0..383
    int b = blockIdx.y;      // 0..15
    int tid = threadIdx.x;
    const float* src = (c < D_) ? (xm + ((size_t)b * D_ + c) * TX_)
                                : (xl + ((size_t)b * D_ + (c - D_)) * TX_);
    const int* pb = path + b * TY_;
    float* ob = out + ((size_t)b * 2 * D_ + c) * TY_;
#pragma unroll
    for (int k = 0; k < 8; k++) {
        int y = tid + k * 256;
        int p = pb[y];
        if ((unsigned)p > 511u) p = 0;                   // clamp: garbage-proof
        ob[y] = src[p];
    }
}

// ============ Kernel G: write one-hot attn ============
__global__ __launch_bounds__(128) void write_attn(const int* __restrict__ path,
                                                  float* __restrict__ attn) {
    int blk = blockIdx.x;            // b*2048 + y
    int b = blk >> 11;
    int y = blk & 2047;
    int tid = threadIdx.x;           // covers x in [4*tid, 4*tid+4)
    int p = path[b * TY_ + y];
    float4 val = make_float4(0.f, 0.f, 0.f, 0.f);
    if ((p >> 2) == tid) {
        int r = p & 3;
        if (r == 0) val.x = 1.f;
        else if (r == 1) val.y = 1.f;
        else if (r == 2) val.z = 1.f;
        else val.w = 1.f;
    }
    ((float4*)attn)[((size_t)blk) * 128 + tid] = val;
}

extern "C" void kernel_launch(void* const* d_in, const int* in_sizes, int n_in,
                              void* d_out, int out_size, void* d_ws, size_t ws_size,
                              hipStream_t stream) {
    const float* x_mean = (const float*)d_in[0];
    const float* x_logs = (const float*)d_in[1];
    const float* z      = (const float*)d_in[2];
    const float* logw   = (const float*)d_in[3];
    float* out = (float*)d_out;

    char* ws = (char*)d_ws;
    float* S            = (float*)(ws + 0);
    float* MS           = (float*)(ws + 6291456);
    float* NC           = (float*)(ws + 12615680);
    unsigned char* dirs = (unsigned char*)(ws + 79724544);
    float* Cpart        = (float*)(ws + 79724544);   // aliases dirs; dead before mas_forward
    int* path           = (int*)(ws + 81821696);

    float* out_main = out;                 // [B,384,TY]
    float* out_l    = out + 12582912;      // [B]
    float* out_attn = out + 12582928;      // [B,TY,TX]

    precomp<<<dim3(B_, 6), dim3(512), 0, stream>>>(x_mean, x_logs, S, MS, Cpart);
    gemm_nc<<<dim3(4, 16, 16), dim3(256), 0, stream>>>(z, S, MS, Cpart, NC);
    mas_forward<<<dim3(B_), dim3(64), 0, stream>>>(NC, dirs);
    mas_backtrack<<<dim3(B_), dim3(64), 0, stream>>>((const unsigned*)dirs, path);
    durations_ll<<<dim3(B_), dim3(512), 0, stream>>>(path, logw, out_l);
    gather_main<<<dim3(384, 16), dim3(256), 0, stream>>>(path, x_mean, x_logs, out_main);
    write_attn<<<dim3(B_ * TY_), dim3(128), 0, stream>>>(path, out_attn);
}

// Round 13
// 673.349 us; speedup vs baseline: 1.5709x; 1.0070x over previous
//
#include <hip/hip_runtime.h>
#include <hip/hip_bf16.h>
#include <math.h>

#define B_   16
#define D_   192
#define TX_  512
#define TY_  2048
#define NEGV (-1e9f)

// -------- workspace layout (bytes) --------
// S    : B*D*TX f32   @ 0          (6,291,456)
// MS   : B*D*TX f32   @ 6291456    (6,291,456)
// NC   : B*TY*TX f32  @ 12615680   (67,108,864)
// dirs : B*2048*64 u8 @ 79724544   (2,097,152)   [aliased: Cpart B*6*TX f32 in
//         first 196,608 B — consumed by gemm_nc BEFORE mas_forward writes dirs]
// path : B*TY  i32    @ 81821696   (131,072)

// -------- output layout (f32 elements) --------
// out_main [B,384,TY] @ 0, l_length [B] @ 12582912, attn [B,TY,TX] @ 12582928

typedef __attribute__((address_space(1))) const float glob_f;
typedef __attribute__((address_space(3))) float       lds_f;
typedef float f32x4 __attribute__((ext_vector_type(4)));   // real clang vector: valid asm "v" operand

// ============ Kernel A: precompute S, MS, partial C (deterministic) ============
__global__ __launch_bounds__(512) void precomp(const float* __restrict__ xm,
                                               const float* __restrict__ xl,
                                               float* __restrict__ S,
                                               float* __restrict__ MS,
                                               float* __restrict__ Cpart) {
    int b = blockIdx.x;
    int p = blockIdx.y;
    int x = threadIdx.x;
    size_t base = ((size_t)b * D_ + p * 32) * TX_;
    const float* mb = xm + base;
    const float* lb = xl + base;
    float* Sb  = S  + base;
    float* MSb = MS + base;
    float c = 0.f;
    for (int d = 0; d < 32; d++) {
        float lg = lb[d * TX_ + x];
        float mn = mb[d * TX_ + x];
        float s  = expf(-2.f * lg);
        float ms = mn * s;
        Sb[d * TX_ + x]  = s;
        MSb[d * TX_ + x] = ms;
        c += -0.9189385332046727f - lg - 0.5f * mn * mn * s;   // nc1 + nc4 terms
    }
    Cpart[(b * 6 + p) * TX_ + x] = c;
}

// ============ Kernel B: NC = A(z)*B(s,ms) + c, f32 128x128 tile, 8x8 micro ============
__global__ __launch_bounds__(256) void gemm_nc(const float* __restrict__ z,
                                               const float* __restrict__ S,
                                               const float* __restrict__ MS,
                                               const float* __restrict__ Cpart,
                                               float* __restrict__ NC) {
    int bx = blockIdx.x;            // 4  -> x tiles of 128
    int by = blockIdx.y;            // 16 -> y tiles of 128
    int b  = blockIdx.z;            // 16
    int tid = threadIdx.x;
    int tx = tid & 15, ty = tid >> 4;
    __shared__ __align__(16) float Zt[16 * 128];
    __shared__ __align__(16) float St[16 * 128];
    __shared__ __align__(16) float MSt[16 * 128];

    float acc[8][8];
#pragma unroll
    for (int i = 0; i < 8; i++)
#pragma unroll
        for (int j = 0; j < 8; j++) acc[i][j] = 0.f;

    int x0 = bx * 128, y0 = by * 128;
    const float* zb  = z  + (size_t)b * D_ * TY_;
    const float* Sb  = S  + (size_t)b * D_ * TX_;
    const float* MSb = MS + (size_t)b * D_ * TX_;

    for (int k0 = 0; k0 < D_; k0 += 16) {
        // stage 3 x (16 rows x 128 cols) via async global->LDS, 16B per lane
#pragma unroll
        for (int j = 0; j < 2; j++) {
            int f = tid + j * 256;          // 0..511 float4 slots
            int kk = f >> 5, c = (f & 31) * 4;
            __builtin_amdgcn_global_load_lds((glob_f*)(zb  + (size_t)(k0 + kk) * TY_ + y0 + c),
                                             (lds_f*)(Zt  + f * 4), 16, 0, 0);
            __builtin_amdgcn_global_load_lds((glob_f*)(Sb  + (size_t)(k0 + kk) * TX_ + x0 + c),
                                             (lds_f*)(St  + f * 4), 16, 0, 0);
            __builtin_amdgcn_global_load_lds((glob_f*)(MSb + (size_t)(k0 + kk) * TX_ + x0 + c),
                                             (lds_f*)(MSt + f * 4), 16, 0, 0);
        }
        __syncthreads();

#pragma unroll 2
        for (int kk = 0; kk < 16; kk++) {
            float4 z0 = *(const float4*)&Zt[kk * 128 + ty * 4];
            float4 z1 = *(const float4*)&Zt[kk * 128 + 64 + ty * 4];
            float4 s0 = *(const float4*)&St[kk * 128 + tx * 4];
            float4 s1 = *(const float4*)&St[kk * 128 + 64 + tx * 4];
            float4 m0 = *(const float4*)&MSt[kk * 128 + tx * 4];
            float4 m1 = *(const float4*)&MSt[kk * 128 + 64 + tx * 4];
            float4 u0, u1;
            u0.x = -0.5f * z0.x * z0.x; u0.y = -0.5f * z0.y * z0.y;
            u0.z = -0.5f * z0.z * z0.z; u0.w = -0.5f * z0.w * z0.w;
            u1.x = -0.5f * z1.x * z1.x; u1.y = -0.5f * z1.y * z1.y;
            u1.z = -0.5f * z1.z * z1.z; u1.w = -0.5f * z1.w * z1.w;
            float zz[8] = {z0.x, z0.y, z0.z, z0.w, z1.x, z1.y, z1.z, z1.w};
            float uu[8] = {u0.x, u0.y, u0.z, u0.w, u1.x, u1.y, u1.z, u1.w};
            float ss[8] = {s0.x, s0.y, s0.z, s0.w, s1.x, s1.y, s1.z, s1.w};
            float mm[8] = {m0.x, m0.y, m0.z, m0.w, m1.x, m1.y, m1.z, m1.w};
#pragma unroll
            for (int i = 0; i < 8; i++)
#pragma unroll
                for (int j = 0; j < 8; j++)
                    acc[i][j] += uu[i] * ss[j] + zz[i] * mm[j];
        }
        __syncthreads();
    }

    // column constants: sum 6 deterministic partials
    float cv[8] = {0, 0, 0, 0, 0, 0, 0, 0};
#pragma unroll
    for (int p = 0; p < 6; p++) {
        float4 c0 = *(const float4*)&Cpart[(b * 6 + p) * TX_ + x0 + tx * 4];
        float4 c1 = *(const float4*)&Cpart[(b * 6 + p) * TX_ + x0 + 64 + tx * 4];
        cv[0] += c0.x; cv[1] += c0.y; cv[2] += c0.z; cv[3] += c0.w;
        cv[4] += c1.x; cv[5] += c1.y; cv[6] += c1.z; cv[7] += c1.w;
    }

#pragma unroll
    for (int i = 0; i < 8; i++) {
        int y = y0 + ty * 4 + (i & 3) + 64 * (i >> 2);
        float4 o0, o1;
        o0.x = acc[i][0] + cv[0]; o0.y = acc[i][1] + cv[1];
        o0.z = acc[i][2] + cv[2]; o0.w = acc[i][3] + cv[3];
        o1.x = acc[i][4] + cv[4]; o1.y = acc[i][5] + cv[5];
        o1.z = acc[i][6] + cv[6]; o1.w = acc[i][7] + cv[7];
        *(float4*)&NC[((size_t)b * TY_ + y) * TX_ + x0 + tx * 4]      = o0;
        *(float4*)&NC[((size_t)b * TY_ + y) * TX_ + x0 + 64 + tx * 4] = o1;
    }
}

// ============ Kernel C: MAS forward DP — asm register ring + DPP boundary ============
// R17 = R16 resubmitted verbatim (R12 round was an infra failure: container
// died before compile/run; the ILP rewrite below is still untested).
// R16 = R15 (verified 236.7us) with row_step rewritten for maximal ILP —
// semantics bit-identical, scheduling freedom maximized:
//  - old v values hoisted to named regs (o0..o7); all 8 fmax/add pairs
//    independent (true recurrence depth per row = 2 ops + DPP).
//  - take-diag bits as 8 INDEPENDENT cmp+cndmask into distinct bit
//    positions, combined by a 3-level OR tree (v_or3-fusable) — replaces
//    the serial 8-deep `bits |=` chain (~4-6cy dep stall per link).
// Everything else unchanged: asm register ring, counted vmcnt(45) with
// tied "+v" waits + sched_barrier(0) (R12 proved removal costs +6.3us),
// DPP wf_sr1 boundary with explicit lane-0 select, byte dirs, readlane
// backtrack. The 2-wave column-split arc remains abandoned.
__global__ __launch_bounds__(64, 1) void mas_forward(const float* __restrict__ NC,
                                                     unsigned char* __restrict__ dirs) {
    int b = blockIdx.x;
    int lane = threadIdx.x;
    const float* ncb = NC + (size_t)b * TY_ * TX_;
    int voff = lane * 32;                      // byte offset of this lane's 8 floats

    // nc[0,0]: compiler-tracked load; its waitcnt lands before the asm ring loads
    float nc00 = ncb[0];
    asm volatile("" :: "v"(nc00));

    float v[8];
#pragma unroll
    for (int j = 0; j < 8; j++) v[j] = NEGV;
    if (lane == 0) v[0] = nc00;

    float bound = NEGV;   // lane-1's v[7] after previous row (via DPP)
    int negi = __float_as_int(NEGV);

    auto row_step = [&](f32x4 a, f32x4 c, int y, bool mask) -> unsigned {
        float o0 = v[0], o1 = v[1], o2 = v[2], o3 = v[3];
        float o4 = v[4], o5 = v[5], o6 = v[6], o7 = v[7];
        float vd0 = (lane == 0) ? NEGV : bound;
        // col 7 first: compute, mask, launch the cross-lane transfer (DPP)
        float v7n = c.w + fmaxf(o7, o6);
        if (mask && y < 511 && lane * 8 + 7 > y) v7n = NEGV;
        bound = __int_as_float(__builtin_amdgcn_update_dpp(
            negi, __float_as_int(v7n), 0x138, 0xf, 0xf, false));
        // independent updates (recurrence depth 2: fmax -> add)
        float n0 = a.x + fmaxf(o0, vd0);
        float n1 = a.y + fmaxf(o1, o0);
        float n2 = a.z + fmaxf(o2, o1);
        float n3 = a.w + fmaxf(o3, o2);
        float n4 = c.x + fmaxf(o4, o3);
        float n5 = c.y + fmaxf(o5, o4);
        float n6 = c.z + fmaxf(o6, o5);
        // independent take-diag bits; 3-level OR tree (no serial chain)
        unsigned b0 = (vd0 > o0) ? 1u : 0u;
        unsigned b1 = (o0 > o1) ? 2u : 0u;
        unsigned b2 = (o1 > o2) ? 4u : 0u;
        unsigned b3 = (o2 > o3) ? 8u : 0u;
        unsigned b4 = (o3 > o4) ? 16u : 0u;
        unsigned b5 = (o4 > o5) ? 32u : 0u;
        unsigned b6 = (o5 > o6) ? 64u : 0u;
        unsigned b7 = (o6 > o7) ? 128u : 0u;
        unsigned bits = ((b0 | b1) | (b2 | b3)) | ((b4 | b5) | (b6 | b7));
        if (mask && y < 511) {
            int xb = lane * 8;
            if (xb + 0 > y) n0 = NEGV;
            if (xb + 1 > y) n1 = NEGV;
            if (xb + 2 > y) n2 = NEGV;
            if (xb + 3 > y) n3 = NEGV;
            if (xb + 4 > y) n4 = NEGV;
            if (xb + 5 > y) n5 = NEGV;
            if (xb + 6 > y) n6 = NEGV;
        }
        v[0] = n0; v[1] = n1; v[2] = n2; v[3] = n3;
        v[4] = n4; v[5] = n5; v[6] = n6; v[7] = v7n;
        return bits;
    };

    f32x4 r0a, r0c, r1a, r1c, r2a, r2c, r3a, r3c, r4a, r4c, r5a, r5c, r6a, r6c, r7a, r7c;
    f32x4 r8a, r8c, r9a, r9c, r10a, r10c, r11a, r11c, r12a, r12c, r13a, r13c, r14a, r14c, r15a, r15c;

    const float* pf = ncb + TX_;                         // next row to load
    unsigned char* dp = dirs + (size_t)b * 2048 * 64;    // dirs row 0 base

#define LOADPAIR(RA, RC)                                                   \
    do {                                                                   \
        asm volatile("global_load_dwordx4 %0, %2, %1 offset:0"             \
                     : "=v"(RA) : "s"(pf), "v"(voff));                     \
        asm volatile("global_load_dwordx4 %0, %2, %1 offset:16"            \
                     : "=v"(RC) : "s"(pf), "v"(voff));                     \
        pf += TX_;                                                         \
    } while (0)

#define STOREBITS(BITS)                                                    \
    asm volatile("global_store_byte %1, %2, %0" :: "s"(dp), "v"(lane), "v"(BITS))

#define PHASE(RA, RC, MASKED)                                              \
    do {                                                                   \
        asm volatile("s_waitcnt vmcnt(45)" : "+v"(RA), "+v"(RC));          \
        __builtin_amdgcn_sched_barrier(0);                                 \
        unsigned bits_ = row_step(RA, RC, y, MASKED);                      \
        STOREBITS(bits_);                                                  \
        LOADPAIR(RA, RC);                                                  \
        dp += 64;                                                          \
        y++;                                                               \
    } while (0)

#define PH16(MASKED)                                                       \
    PHASE(r0a, r0c, MASKED);  PHASE(r1a, r1c, MASKED);                     \
    PHASE(r2a, r2c, MASKED);  PHASE(r3a, r3c, MASKED);                     \
    PHASE(r4a, r4c, MASKED);  PHASE(r5a, r5c, MASKED);                     \
    PHASE(r6a, r6c, MASKED);  PHASE(r7a, r7c, MASKED);                     \
    PHASE(r8a, r8c, MASKED);  PHASE(r9a, r9c, MASKED);                     \
    PHASE(r10a, r10c, MASKED); PHASE(r11a, r11c, MASKED);                  \
    PHASE(r12a, r12c, MASKED); PHASE(r13a, r13c, MASKED);                  \
    PHASE(r14a, r14c, MASKED); PHASE(r15a, r15c, MASKED);

    // prologue: rows 1..16 into ring slots 0..15, then drain once
    LOADPAIR(r0a, r0c);   LOADPAIR(r1a, r1c);   LOADPAIR(r2a, r2c);   LOADPAIR(r3a, r3c);
    LOADPAIR(r4a, r4c);   LOADPAIR(r5a, r5c);   LOADPAIR(r6a, r6c);   LOADPAIR(r7a, r7c);
    LOADPAIR(r8a, r8c);   LOADPAIR(r9a, r9c);   LOADPAIR(r10a, r10c); LOADPAIR(r11a, r11c);
    LOADPAIR(r12a, r12c); LOADPAIR(r13a, r13c); LOADPAIR(r14a, r14c); LOADPAIR(r15a, r15c);
    asm volatile("s_waitcnt vmcnt(0)" ::: "memory");
    __builtin_amdgcn_sched_barrier(0);

    int y = 1;
    // masked phase: rows 1..512 (mask condition y<511 applied inside)
    for (int t = 0; t < 32; t++) {
        PH16(true)
    }
    // unmasked phase: rows 513..2016
    for (int t = 32; t < 126; t++) {
        PH16(false)
    }
    // rows 2017..2031 with prefetch (loads rows 2033..2047)
    PHASE(r0a, r0c, false);  PHASE(r1a, r1c, false);
    PHASE(r2a, r2c, false);  PHASE(r3a, r3c, false);
    PHASE(r4a, r4c, false);  PHASE(r5a, r5c, false);
    PHASE(r6a, r6c, false);  PHASE(r7a, r7c, false);
    PHASE(r8a, r8c, false);  PHASE(r9a, r9c, false);
    PHASE(r10a, r10c, false); PHASE(r11a, r11c, false);
    PHASE(r12a, r12c, false); PHASE(r13a, r13c, false);
    PHASE(r14a, r14c, false);
    // row 2032: wait(45) exactly releases its loads; no further prefetch
    {
        asm volatile("s_waitcnt vmcnt(45)" : "+v"(r15a), "+v"(r15c));
        __builtin_amdgcn_sched_barrier(0);
        unsigned bits_ = row_step(r15a, r15c, y, false);
        STOREBITS(bits_);
        dp += 64;
        y++;
    }

    // epilogue: rows 2033..2047 from ring slots 0..14. vmcnt(1): newest op is
    // the row-2032 store; all ring loads (older) are complete after this.
    asm volatile("s_waitcnt vmcnt(1)"
                 : "+v"(r0a), "+v"(r0c), "+v"(r1a), "+v"(r1c),
                   "+v"(r2a), "+v"(r2c), "+v"(r3a), "+v"(r3c),
                   "+v"(r4a), "+v"(r4c), "+v"(r5a), "+v"(r5c),
                   "+v"(r6a), "+v"(r6c), "+v"(r7a), "+v"(r7c));
    asm volatile("s_waitcnt vmcnt(1)"
                 : "+v"(r8a), "+v"(r8c), "+v"(r9a), "+v"(r9c),
                   "+v"(r10a), "+v"(r10c), "+v"(r11a), "+v"(r11c),
                   "+v"(r12a), "+v"(r12c), "+v"(r13a), "+v"(r13c),
                   "+v"(r14a), "+v"(r14c));
    __builtin_amdgcn_sched_barrier(0);
    {
        unsigned bb;
        bb = row_step(r0a, r0c, y, false);  STOREBITS(bb); dp += 64; y++;
        bb = row_step(r1a, r1c, y, false);  STOREBITS(bb); dp += 64; y++;
        bb = row_step(r2a, r2c, y, false);  STOREBITS(bb); dp += 64; y++;
        bb = row_step(r3a, r3c, y, false);  STOREBITS(bb); dp += 64; y++;
        bb = row_step(r4a, r4c, y, false);  STOREBITS(bb); dp += 64; y++;
        bb = row_step(r5a, r5c, y, false);  STOREBITS(bb); dp += 64; y++;
        bb = row_step(r6a, r6c, y, false);  STOREBITS(bb); dp += 64; y++;
        bb = row_step(r7a, r7c, y, false);  STOREBITS(bb); dp += 64; y++;
        bb = row_step(r8a, r8c, y, false);  STOREBITS(bb); dp += 64; y++;
        bb = row_step(r9a, r9c, y, false);  STOREBITS(bb); dp += 64; y++;
        bb = row_step(r10a, r10c, y, false); STOREBITS(bb); dp += 64; y++;
        bb = row_step(r11a, r11c, y, false); STOREBITS(bb); dp += 64; y++;
        bb = row_step(r12a, r12c, y, false); STOREBITS(bb); dp += 64; y++;
        bb = row_step(r13a, r13c, y, false); STOREBITS(bb); dp += 64; y++;
        bb = row_step(r14a, r14c, y, false); STOREBITS(bb);
    }

#undef PH16
#undef PHASE
#undef STOREBITS
#undef LOADPAIR
}

// ============ Kernel D: backtrack — readlane/scalar (verified R12) ============
// t is uniform -> readlane replaces the 3 DS-pipe shfl round trips per step
// with 3 VALU ops; the idx chain scalarizes. Byte-dirs layout (64B/row).
__global__ __launch_bounds__(64, 1) void mas_backtrack(const unsigned* __restrict__ dirs,
                                                       int* __restrict__ path) {
    int b = blockIdx.x;
    int lane = threadIdx.x;
    const unsigned* db = dirs + (size_t)b * 2048 * 16;   // 16 dwords per row
    int idx = TX_ - 1;                                   // path[2047]

    for (int y_hi = 2047; y_hi >= 1; y_hi -= 64) {
        int wb = (idx >> 5) - 2;
        if (wb < 0) wb = 0;
        if (wb > 13) wb = 13;                            // clamp: garbage-proof
        int base = wb << 5;
        int y = y_hi - lane;
        unsigned w0 = 0, w1 = 0, w2 = 0;
        if (y >= 1) {
            const unsigned* r = db + (size_t)(y - 1) * 16 + wb;
            w0 = r[0]; w1 = r[1]; w2 = r[2];
        }
        int steps = (y_hi < 64) ? y_hi : 64;
        int my_path = 0;
#pragma unroll
        for (int t = 0; t < 64; t++) {
            if (t < steps) {
                unsigned u0 = (unsigned)__builtin_amdgcn_readlane((int)w0, t);
                unsigned u1 = (unsigned)__builtin_amdgcn_readlane((int)w1, t);
                unsigned u2 = (unsigned)__builtin_amdgcn_readlane((int)w2, t);
                if (lane == t) my_path = idx;
                int off = idx - base;
                unsigned w = (off < 32) ? u0 : ((off < 64) ? u1 : u2);
                idx -= (int)((w >> (off & 31)) & 1u);
            }
        }
        if (lane < steps) path[b * TY_ + (y_hi - lane)] = my_path;
    }
    if (lane == 0) path[b * TY_ + 0] = idx;
}

// ============ Kernel E: durations + l_length ============
__global__ __launch_bounds__(512) void durations_ll(const int* __restrict__ path,
                                                    const float* __restrict__ logw,
                                                    float* __restrict__ out_l) {
    int b = blockIdx.x;
    int tid = threadIdx.x;
    __shared__ int wcnt[TX_];
    __shared__ float partial[8];
    wcnt[tid] = 0;
    __syncthreads();
    for (int y = tid; y < TY_; y += 512) {
        int p = path[b * TY_ + y];
        if ((unsigned)p > 511u) p = 0;                   // clamp: garbage-proof
        atomicAdd(&wcnt[p], 1);
    }
    __syncthreads();
    float t = logw[b * TX_ + tid] - logf((float)wcnt[tid] + 1e-6f);
    float sq = t * t;
#pragma unroll
    for (int off = 32; off > 0; off >>= 1) sq += __shfl_down(sq, off);
    if ((tid & 63) == 0) partial[tid >> 6] = sq;
    __syncthreads();
    if (tid == 0) {
        float s = 0.f;
#pragma unroll
        for (int i = 0; i < 8; i++) s += partial[i];
        out_l[b] = s;
    }
}

// ============ Kernel F: gather out_main ============
__global__ __launch_bounds__(256) void gather_main(const int* __restrict__ path,
                                                   const float* __restrict__ xm,
                                                   const float* __restrict__ xl,
                                                   float* __restrict__ out) {
    int c = blockIdx.x;      // 0..383
    int b = blockIdx.y;      // 0..15
    int tid = threadIdx.x;
    const float* src = (c < D_) ? (xm + ((size_t)b * D_ + c) * TX_)
                                : (xl + ((size_t)b * D_ + (c - D_)) * TX_);
    const int* pb = path + b * TY_;
    float* ob = out + ((size_t)b * 2 * D_ + c) * TY_;
#pragma unroll
    for (int k = 0; k < 8; k++) {
        int y = tid + k * 256;
        int p = pb[y];
        if ((unsigned)p > 511u) p = 0;                   // clamp: garbage-proof
        ob[y] = src[p];
    }
}

// ============ Kernel G: write one-hot attn ============
__global__ __launch_bounds__(128) void write_attn(const int* __restrict__ path,
                                                  float* __restrict__ attn) {
    int blk = blockIdx.x;            // b*2048 + y
    int b = blk >> 11;
    int y = blk & 2047;
    int tid = threadIdx.x;           // covers x in [4*tid, 4*tid+4)
    int p = path[b * TY_ + y];
    float4 val = make_float4(0.f, 0.f, 0.f, 0.f);
    if ((p >> 2) == tid) {
        int r = p & 3;
        if (r == 0) val.x = 1.f;
        else if (r == 1) val.y = 1.f;
        else if (r == 2) val.z = 1.f;
        else val.w = 1.f;
    }
    ((float4*)attn)[((size_t)blk) * 128 + tid] = val;
}

extern "C" void kernel_launch(void* const* d_in, const int* in_sizes, int n_in,
                              void* d_out, int out_size, void* d_ws, size_t ws_size,
                              hipStream_t stream) {
    const float* x_mean = (const float*)d_in[0];
    const float* x_logs = (const float*)d_in[1];
    const float* z      = (const float*)d_in[2];
    const float* logw   = (const float*)d_in[3];
    float* out = (float*)d_out;

    char* ws = (char*)d_ws;
    float* S            = (float*)(ws + 0);
    float* MS           = (float*)(ws + 6291456);
    float* NC           = (float*)(ws + 12615680);
    unsigned char* dirs = (unsigned char*)(ws + 79724544);
    float* Cpart        = (float*)(ws + 79724544);   // aliases dirs; dead before mas_forward
    int* path           = (int*)(ws + 81821696);

    float* out_main = out;                 // [B,384,TY]
    float* out_l    = out + 12582912;      // [B]
    float* out_attn = out + 12582928;      // [B,TY,TX]

    precomp<<<dim3(B_, 6), dim3(512), 0, stream>>>(x_mean, x_logs, S, MS, Cpart);
    gemm_nc<<<dim3(4, 16, 16), dim3(256), 0, stream>>>(z, S, MS, Cpart, NC);
    mas_forward<<<dim3(B_), dim3(64), 0, stream>>>(NC, dirs);
    mas_backtrack<<<dim3(B_), dim3(64), 0, stream>>>((const unsigned*)dirs, path);
    durations_ll<<<dim3(B_), dim3(512), 0, stream>>>(path, logw, out_l);
    gather_main<<<dim3(384, 16), dim3(256), 0, stream>>>(path, x_mean, x_logs, out_main);
    write_attn<<<dim3(B_ * TY_), dim3(128), 0, stream>>>(path, out_attn);
}